// Round 16
// baseline (359.143 us; speedup 1.0000x reference)
//
#include <hip/hip_runtime.h>
#include <math.h>

// ---------------------------------------------------------------------------
// GAT encoder: 3 GATConv layers (H=4,4,1) + ELU + global max pool.
// Layer 0: aggregate-then-project with INT8 x gather (per-node scale from
//   k_att0's wave max, scale+bias folded into preamble weights) -> post-GEMM.
// Layer 1: z-GEMM emits INT8 z (per-128x64-tile scale); aggregate gathers
//   uint8 at the XCD-compulsory fetch floor, scales folded in preamble,
//   head-major LDS weights PADDED [4][4][68] (bank-conflict-free b128 reads).
// Layer 2: z-GEMM bf16 out + aggregate + fused atomicMax pool.
// CSR build: bucketed counting sort (dense writes). 3-pass parallel scans.
// ---------------------------------------------------------------------------

typedef __attribute__((ext_vector_type(8))) short short8v;
typedef __attribute__((ext_vector_type(16))) float f32x16;

constexpr int CH = 4096;  // edges per bucketing block

__device__ __forceinline__ float lrelu(float x) { return x > 0.f ? x : 0.2f * x; }

__device__ __forceinline__ unsigned short f2bf(float x) {  // RNE
    unsigned u = __float_as_uint(x);
    return (unsigned short)((u + 0x7FFFu + ((u >> 16) & 1u)) >> 16);
}
__device__ __forceinline__ float bf2f(unsigned short h) {
    return __uint_as_float(((unsigned)h) << 16);
}
__device__ __forceinline__ float readlane_f(float v, int l) {
    return __uint_as_float((unsigned)__builtin_amdgcn_readlane((int)__float_as_uint(v), l));
}

// ----------------------------- CSR build (bucketed) --------------------------
__global__ __launch_bounds__(256) void k_hist(const int* __restrict__ dst, int E, int N,
                                              int* __restrict__ deg, int* __restrict__ bcnt) {
    __shared__ int h[1024];
    for (int b = threadIdx.x; b < 1024; b += 256) h[b] = 0;
    __syncthreads();
    const int base = blockIdx.x * CH;
    const int Et = E + N;
    for (int i = threadIdx.x; i < CH; i += 256) {
        const int e = base + i;
        if (e < Et) {
            const int d = (e < E) ? dst[e] : (e - E);
            atomicAdd(&deg[d], 1);
            atomicAdd(&h[d >> 6], 1);
        }
    }
    __syncthreads();
    for (int b = threadIdx.x; b < 1024; b += 256)
        if (h[b]) atomicAdd(&bcnt[b], h[b]);
}

__global__ __launch_bounds__(256) void k_scan1(const int* __restrict__ deg,
                                               int* __restrict__ incl,
                                               int* __restrict__ bsum, int N) {
    const int i = blockIdx.x * 256 + threadIdx.x;
    const int lane = threadIdx.x & 63;
    const int wv = threadIdx.x >> 6;
    int sc = (i < N) ? deg[i] : 0;
#pragma unroll
    for (int off = 1; off < 64; off <<= 1) {
        int t = __shfl_up(sc, off, 64);
        if (lane >= off) sc += t;
    }
    __shared__ int wsum[4];
    if (lane == 63) wsum[wv] = sc;
    __syncthreads();
    int woff = 0;
#pragma unroll
    for (int k = 0; k < 3; k++)
        if (wv > k) woff += wsum[k];
    sc += woff;
    if (i < N) incl[i] = sc;
    if (threadIdx.x == 255) bsum[blockIdx.x] = sc;
}

__global__ __launch_bounds__(1024) void k_scan2(int* __restrict__ bsum, int nb,
                                                const int* __restrict__ bcnt,
                                                int* __restrict__ bbase,
                                                int* __restrict__ bcur, int nbk) {
    const int t = threadIdx.x;
    const int lane = t & 63;
    const int wv = t >> 6;
    const bool nodeScan = (blockIdx.x == 0);
    const int cnt = nodeScan ? nb : nbk;
    int v = 0;
    if (t < cnt) v = nodeScan ? bsum[t] : bcnt[t];
    int sc = v;
#pragma unroll
    for (int off = 1; off < 64; off <<= 1) {
        int u = __shfl_up(sc, off, 64);
        if (lane >= off) sc += u;
    }
    __shared__ int wsum[16];
    if (lane == 63) wsum[wv] = sc;
    __syncthreads();
    int woff = 0;
#pragma unroll
    for (int k = 0; k < 15; k++)
        if (wv > k) woff += wsum[k];
    sc += woff;
    if (t < cnt) {
        if (nodeScan) {
            bsum[t] = sc;
        } else {
            bbase[t] = sc - v;
            bcur[t] = sc - v;
        }
    }
}

__global__ void k_scan3(const int* __restrict__ deg, const int* __restrict__ incl,
                        const int* __restrict__ bsum, int* __restrict__ rowptr,
                        int* __restrict__ cursor, int N, int nb) {
    int i = blockIdx.x * 256 + threadIdx.x;
    if (i < N) {
        const int off = (blockIdx.x > 0) ? bsum[blockIdx.x - 1] : 0;
        const int excl = incl[i] + off - deg[i];
        rowptr[i] = excl;
        cursor[i] = excl;
        if (i == N - 1) rowptr[N] = bsum[nb - 1];
    }
}

__global__ __launch_bounds__(256) void k_bucket(const int* __restrict__ src,
                                                const int* __restrict__ dst, int E, int N,
                                                int* __restrict__ bcur,
                                                uint2* __restrict__ rec) {
    __shared__ int h[1024];
    __shared__ int boff[1024];
    for (int b = threadIdx.x; b < 1024; b += 256) h[b] = 0;
    __syncthreads();
    const int base = blockIdx.x * CH;
    const int Et = E + N;
    for (int i = threadIdx.x; i < CH; i += 256) {
        const int e = base + i;
        if (e < Et) {
            const int d = (e < E) ? dst[e] : (e - E);
            atomicAdd(&h[d >> 6], 1);
        }
    }
    __syncthreads();
    for (int b = threadIdx.x; b < 1024; b += 256)
        boff[b] = h[b] ? atomicAdd(&bcur[b], h[b]) : 0;
    __syncthreads();
    for (int b = threadIdx.x; b < 1024; b += 256) h[b] = 0;
    __syncthreads();
    for (int i = threadIdx.x; i < CH; i += 256) {
        const int e = base + i;
        if (e < Et) {
            int d, s;
            if (e < E) {
                d = dst[e];
                s = src[e];
            } else {
                d = e - E;
                s = d;
            }
            const int r = atomicAdd(&h[d >> 6], 1);
            rec[boff[d >> 6] + r] = make_uint2((unsigned)s, (unsigned)d);
        }
    }
}

__global__ void k_place(const uint2* __restrict__ rec, int Et, int* __restrict__ cursor,
                        int* __restrict__ col) {
    int e = blockIdx.x * 256 + threadIdx.x;
    if (e < Et) {
        const uint2 rd = rec[e];
        const int p = atomicAdd(&cursor[(int)rd.y], 1);
        col[p] = (int)rd.x;
    }
}

// ----------------------------- fused setup -----------------------------------
__global__ void k_setup(const float* __restrict__ W0, const float* __restrict__ W1,
                        const float* __restrict__ W2, const float* __restrict__ as0,
                        const float* __restrict__ ad0,
                        unsigned short* __restrict__ wt0h, unsigned short* __restrict__ wt0l,
                        unsigned short* __restrict__ wt1h, unsigned short* __restrict__ wt1l,
                        unsigned short* __restrict__ wt2h, unsigned short* __restrict__ wt2l,
                        float* __restrict__ vs0, float* __restrict__ vd0,
                        unsigned* __restrict__ enc, int encM) {
    const int b = blockIdx.x;
    const int t = threadIdx.x;
    if (b < 64) {
        const int i = b * 256 + t;
        const int c = i / 64, k = i % 64;
        const float xw = W0[(size_t)k * 256 + c];
        const unsigned short h = f2bf(xw);
        wt0h[i] = h;
        wt0l[i] = f2bf(xw - bf2f(h));
    } else if (b < 320) {
        const int i = (b - 64) * 256 + t;
        const int c = i / 256, k = i % 256;
        const float xw = W1[(size_t)k * 256 + c];
        const unsigned short h = f2bf(xw);
        wt1h[i] = h;
        wt1l[i] = f2bf(xw - bf2f(h));
    } else if (b < 384) {
        const int i = (b - 320) * 256 + t;
        const int c = i / 256, k = i % 256;
        const float xw = W2[(size_t)k * 64 + c];
        const unsigned short h = f2bf(xw);
        wt2h[i] = h;
        wt2l[i] = f2bf(xw - bf2f(h));
    } else if (b == 384) {
        const int k = t;
        if (k < 64) {
            for (int h = 0; h < 4; h++) {
                float s = 0.f, d = 0.f;
                for (int c = 0; c < 64; c++) {
                    float w = W0[(size_t)k * 256 + h * 64 + c];
                    s = fmaf(w, as0[h * 64 + c], s);
                    d = fmaf(w, ad0[h * 64 + c], d);
                }
                vs0[h * 64 + k] = s;
                vd0[h * 64 + k] = d;
            }
        }
    } else {
        const int i = (b - 385) * 256 + t;
        if (i < encM) enc[i] = 0u;
    }
}

// As0/Ad0 (wave per node); also emits per-node-scaled biased uint8 x + scale.
__global__ __launch_bounds__(256) void k_att0(
    const float* __restrict__ X, const float* __restrict__ vs, const float* __restrict__ vd,
    float* __restrict__ As, float* __restrict__ Ad, unsigned char* __restrict__ xq,
    float* __restrict__ scl, int N) {
    const int n = blockIdx.x * 4 + (threadIdx.x >> 6);
    const int lane = threadIdx.x & 63;
    if (n >= N) return;
    const float xv = X[(size_t)n * 64 + lane];

    float am = fabsf(xv);
#pragma unroll
    for (int off = 1; off < 64; off <<= 1) am = fmaxf(am, __shfl_xor(am, off, 64));
    am = fmaxf(am, 1e-20f);
    const float rs = 127.f / am;
    int q = __float2int_rn(xv * rs) + 128;
    q = min(255, max(0, q));
    xq[(size_t)n * 64 + lane] = (unsigned char)q;
    if (lane == 0) scl[n] = am * (1.f / 127.f);

#pragma unroll
    for (int h = 0; h < 4; h++) {
        float ps = xv * vs[h * 64 + lane];
        float pd = xv * vd[h * 64 + lane];
#pragma unroll
        for (int off = 1; off < 64; off <<= 1) {
            ps += __shfl_xor(ps, off, 64);
            pd += __shfl_xor(pd, off, 64);
        }
        if (lane == 0) {
            As[(size_t)n * 4 + h] = ps;
            Ad[(size_t)n * 4 + h] = pd;
        }
    }
}

// ----------------------------- layer-0 x-aggregate (int8) --------------------
// Wave per node, lane = x-dim. 64B/edge uint8 gather. Per-source scale folded
// into the 4 head weights in the preamble; -128 bias corr accumulated in the
// preamble (gather-independent). Denominators pre-scale.
__global__ __launch_bounds__(256) void k_aggx(
    const unsigned char* __restrict__ Xq, const float* __restrict__ scl,
    const float* __restrict__ As, const float* __restrict__ Ad,
    const int* __restrict__ rowptr, const int* __restrict__ col,
    unsigned short* __restrict__ ohi, unsigned short* __restrict__ olo, int N) {
    __shared__ float wlds[4][64][4];
    const int wv = threadIdx.x >> 6;
    const int n = blockIdx.x * 4 + wv;
    const int lane = threadIdx.x & 63;
    if (n >= N) return;

    const int start = rowptr[n];
    const int total = rowptr[n + 1] - start;  // includes self-loop
    const int* __restrict__ cp = col + start;
    const float4 adn = *reinterpret_cast<const float4*>(Ad + (size_t)n * 4);

    float a0 = 0.f, a1 = 0.f, a2 = 0.f, a3 = 0.f;
    float4 dv = make_float4(0.f, 0.f, 0.f, 0.f);
    float4 cr = make_float4(0.f, 0.f, 0.f, 0.f);

    for (int base = 0; base < total; base += 64) {
        const int cnt = min(64, total - base);
        const int i = base + lane;
        int s = 0;
        float4 w = make_float4(0.f, 0.f, 0.f, 0.f);
        if (i < total) {
            s = cp[i];
            const float4 av = *reinterpret_cast<const float4*>(As + (size_t)s * 4);
            w.x = __expf(lrelu(av.x + adn.x));
            w.y = __expf(lrelu(av.y + adn.y));
            w.z = __expf(lrelu(av.z + adn.z));
            w.w = __expf(lrelu(av.w + adn.w));
        }
        dv.x += w.x; dv.y += w.y; dv.z += w.z; dv.w += w.w;
        if (i < total) {
            const float sc = scl[s];
            w.x *= sc; w.y *= sc; w.z *= sc; w.w *= sc;
        }
        cr.x += w.x; cr.y += w.y; cr.z += w.z; cr.w += w.w;
        *reinterpret_cast<float4*>(&wlds[wv][lane][0]) = w;

        int jj = 0;
        for (; jj + 4 <= cnt; jj += 4) {
            int sb[4];
            float4 wj[4];
            float xv[4];
#pragma unroll
            for (int u = 0; u < 4; u++) {
                sb[u] = __builtin_amdgcn_readlane(s, jj + u);
                wj[u] = *reinterpret_cast<const float4*>(&wlds[wv][jj + u][0]);
            }
#pragma unroll
            for (int u = 0; u < 4; u++)
                xv[u] = (float)Xq[(((unsigned)sb[u]) << 6) + (unsigned)lane];
#pragma unroll
            for (int u = 0; u < 4; u++) {
                a0 = fmaf(wj[u].x, xv[u], a0);
                a1 = fmaf(wj[u].y, xv[u], a1);
                a2 = fmaf(wj[u].z, xv[u], a2);
                a3 = fmaf(wj[u].w, xv[u], a3);
            }
        }
        for (; jj < cnt; jj++) {
            const int s0 = __builtin_amdgcn_readlane(s, jj);
            const float4 wj = *reinterpret_cast<const float4*>(&wlds[wv][jj][0]);
            const float xv = (float)Xq[(((unsigned)s0) << 6) + (unsigned)lane];
            a0 = fmaf(wj.x, xv, a0);
            a1 = fmaf(wj.y, xv, a1);
            a2 = fmaf(wj.z, xv, a2);
            a3 = fmaf(wj.w, xv, a3);
        }
    }

#pragma unroll
    for (int off = 1; off < 64; off <<= 1) {
        dv.x += __shfl_xor(dv.x, off, 64);
        dv.y += __shfl_xor(dv.y, off, 64);
        dv.z += __shfl_xor(dv.z, off, 64);
        dv.w += __shfl_xor(dv.w, off, 64);
        cr.x += __shfl_xor(cr.x, off, 64);
        cr.y += __shfl_xor(cr.y, off, 64);
        cr.z += __shfl_xor(cr.z, off, 64);
        cr.w += __shfl_xor(cr.w, off, 64);
    }
    a0 -= 128.f * cr.x;
    a1 -= 128.f * cr.y;
    a2 -= 128.f * cr.z;
    a3 -= 128.f * cr.w;

    const float o[4] = {a0 / (dv.x + 1e-16f), a1 / (dv.y + 1e-16f),
                        a2 / (dv.z + 1e-16f), a3 / (dv.w + 1e-16f)};
#pragma unroll
    for (int h = 0; h < 4; h++) {
        const unsigned short hb = f2bf(o[h]);
        ohi[(size_t)n * 256 + h * 64 + lane] = hb;
        olo[(size_t)n * 256 + h * 64 + lane] = f2bf(o[h] - bf2f(hb));
    }
}

// ----------------------------- post-GEMM (layer 0) ---------------------------
__global__ __launch_bounds__(256) void k_gemm_pe(
    const unsigned short* __restrict__ Ahi, const unsigned short* __restrict__ Alo,
    const unsigned short* __restrict__ Bhi, const unsigned short* __restrict__ Blo,
    const float* __restrict__ bias, unsigned short* __restrict__ Ohi, int N) {
    constexpr int LD = 40, BM = 128, K = 64;
    __shared__ unsigned short sa[2][BM * LD];
    __shared__ unsigned short sb[2][64 * LD];

    const int tid = threadIdx.x;
    const int n0 = blockIdx.x * BM;
    const int hh = blockIdx.y;
    const int wid = tid >> 6, lane = tid & 63;

    const unsigned short* __restrict__ Ah = Ahi + hh * 64;
    const unsigned short* __restrict__ Al = Alo + hh * 64;
    const unsigned short* __restrict__ Bh = Bhi + hh * 64 * K;
    const unsigned short* __restrict__ Bl = Blo + hh * 64 * K;

    f32x16 acc[2];
#pragma unroll
    for (int n = 0; n < 2; n++)
#pragma unroll
        for (int i = 0; i < 16; i++) acc[n][i] = 0.f;

    const int srow = tid >> 2, schk = tid & 3;

    for (int kb = 0; kb < K; kb += 32) {
        __syncthreads();
#pragma unroll
        for (int rr = 0; rr < 2; rr++) {
            const int r = srow + rr * 64;
            const int row = n0 + r;
            short8v vh = {0, 0, 0, 0, 0, 0, 0, 0}, vl = {0, 0, 0, 0, 0, 0, 0, 0};
            if (row < N) {
                vh = *reinterpret_cast<const short8v*>(Ah + (size_t)row * 256 + kb + schk * 8);
                vl = *reinterpret_cast<const short8v*>(Al + (size_t)row * 256 + kb + schk * 8);
            }
            *reinterpret_cast<short8v*>(&sa[0][r * LD + schk * 8]) = vh;
            *reinterpret_cast<short8v*>(&sa[1][r * LD + schk * 8]) = vl;
        }
        {
            const short8v vh =
                *reinterpret_cast<const short8v*>(Bh + (size_t)srow * K + kb + schk * 8);
            const short8v vl =
                *reinterpret_cast<const short8v*>(Bl + (size_t)srow * K + kb + schk * 8);
            *reinterpret_cast<short8v*>(&sb[0][srow * LD + schk * 8]) = vh;
            *reinterpret_cast<short8v*>(&sb[1][srow * LD + schk * 8]) = vl;
        }
        __syncthreads();
#pragma unroll
        for (int ks = 0; ks < 2; ks++) {
            const int koff = ks * 16 + (lane >> 5) * 8;
            const int ar = wid * 32 + (lane & 31);
            const short8v ah = *reinterpret_cast<const short8v*>(&sa[0][ar * LD + koff]);
            const short8v al = *reinterpret_cast<const short8v*>(&sa[1][ar * LD + koff]);
            short8v bh[2], bl[2];
#pragma unroll
            for (int n = 0; n < 2; n++) {
                const int br = n * 32 + (lane & 31);
                bh[n] = *reinterpret_cast<const short8v*>(&sb[0][br * LD + koff]);
                bl[n] = *reinterpret_cast<const short8v*>(&sb[1][br * LD + koff]);
            }
#pragma unroll
            for (int n = 0; n < 2; n++) {
                acc[n] = __builtin_amdgcn_mfma_f32_32x32x16_bf16(ah, bh[n], acc[n], 0, 0, 0);
                acc[n] = __builtin_amdgcn_mfma_f32_32x32x16_bf16(ah, bl[n], acc[n], 0, 0, 0);
                acc[n] = __builtin_amdgcn_mfma_f32_32x32x16_bf16(al, bh[n], acc[n], 0, 0, 0);
            }
        }
    }

    const int rowb = n0 + wid * 32 + 4 * (lane >> 5);
#pragma unroll
    for (int n = 0; n < 2; n++) {
        const int c = (lane & 31) + n * 32;
        const float bv = bias[hh * 64 + c];
#pragma unroll
        for (int r = 0; r < 16; r++) {
            const int row = rowb + (r & 3) + 8 * (r >> 2);
            if (row < N) {
                float ov = acc[n][r] + bv;
                ov = (ov > 0.f) ? ov : expm1f(ov);
                Ohi[(size_t)row * 256 + hh * 64 + c] = f2bf(ov);
            }
        }
    }
}

// ----------------------------- z GEMM (layers 1,2) ---------------------------
template <int K, int COLS, int BM, int BN, int WN, int OUTMODE>
__global__ __launch_bounds__(256) void k_gemm_z(
    const unsigned short* __restrict__ Ahi,
    const unsigned short* __restrict__ Bhi, const unsigned short* __restrict__ Blo,
    const float* __restrict__ att_src, const float* __restrict__ att_dst,
    unsigned short* __restrict__ Zb, unsigned char* __restrict__ Zq,
    float* __restrict__ scq, float* __restrict__ As, float* __restrict__ Ad, int N) {
    constexpr int LD = 40;
    constexpr int WAVES_N = BN / WN;
    constexpr int WAVES_M = 4 / WAVES_N;
    constexpr int WM = BM / WAVES_M;
    constexpr int MW = WM / 32, NW = WN / 32;
    constexpr int H = COLS / 64;
    __shared__ unsigned short sa[BM * LD];
    __shared__ unsigned short sb[2][BN * LD];

    const int tid = threadIdx.x;
    const int n0 = blockIdx.x * BM;
    const int c0 = blockIdx.y * BN;
    const int wid = tid >> 6, lane = tid & 63;
    const int wr = wid / WAVES_N, wc = wid % WAVES_N;

    f32x16 acc[MW][NW];
#pragma unroll
    for (int m = 0; m < MW; m++)
#pragma unroll
        for (int n = 0; n < NW; n++)
#pragma unroll
            for (int i = 0; i < 16; i++) acc[m][n][i] = 0.f;

    const int srow = tid >> 2, schk = tid & 3;

    for (int kb = 0; kb < K; kb += 32) {
        __syncthreads();
#pragma unroll
        for (int rr = 0; rr < BM / 64; rr++) {
            const int r = srow + rr * 64;
            const int row = n0 + r;
            short8v vh = {0, 0, 0, 0, 0, 0, 0, 0};
            if (row < N)
                vh = *reinterpret_cast<const short8v*>(Ahi + (size_t)row * K + kb + schk * 8);
            *reinterpret_cast<short8v*>(&sa[r * LD + schk * 8]) = vh;
        }
#pragma unroll
        for (int rr = 0; rr < BN / 64; rr++) {
            const int cc = srow + rr * 64;
            const short8v vh =
                *reinterpret_cast<const short8v*>(Bhi + (size_t)(c0 + cc) * K + kb + schk * 8);
            const short8v vl =
                *reinterpret_cast<const short8v*>(Blo + (size_t)(c0 + cc) * K + kb + schk * 8);
            *reinterpret_cast<short8v*>(&sb[0][cc * LD + schk * 8]) = vh;
            *reinterpret_cast<short8v*>(&sb[1][cc * LD + schk * 8]) = vl;
        }
        __syncthreads();
#pragma unroll
        for (int ks = 0; ks < 2; ks++) {
            const int koff = ks * 16 + (lane >> 5) * 8;
            short8v ah[MW], bh[NW], bl[NW];
#pragma unroll
            for (int m = 0; m < MW; m++) {
                const int ar = wr * WM + m * 32 + (lane & 31);
                ah[m] = *reinterpret_cast<const short8v*>(&sa[ar * LD + koff]);
            }
#pragma unroll
            for (int n = 0; n < NW; n++) {
                const int br = wc * WN + n * 32 + (lane & 31);
                bh[n] = *reinterpret_cast<const short8v*>(&sb[0][br * LD + koff]);
                bl[n] = *reinterpret_cast<const short8v*>(&sb[1][br * LD + koff]);
            }
#pragma unroll
            for (int m = 0; m < MW; m++)
#pragma unroll
                for (int n = 0; n < NW; n++) {
                    acc[m][n] = __builtin_amdgcn_mfma_f32_32x32x16_bf16(ah[m], bh[n], acc[m][n], 0, 0, 0);
                    acc[m][n] = __builtin_amdgcn_mfma_f32_32x32x16_bf16(ah[m], bl[n], acc[m][n], 0, 0, 0);
                }
        }
    }

    const int colb = c0 + wc * WN + (lane & 31);
    const int rowb = n0 + wr * WM + 4 * (lane >> 5);

    if constexpr (OUTMODE == 0) {
#pragma unroll
        for (int m = 0; m < MW; m++)
#pragma unroll
            for (int n = 0; n < NW; n++)
#pragma unroll
                for (int r = 0; r < 16; r++) {
                    const int row = rowb + m * 32 + (r & 3) + 8 * (r >> 2);
                    if (row < N) Zb[(size_t)row * COLS + colb + n * 32] = f2bf(acc[m][n][r]);
                }
    } else {
        float lmax = 0.f;
#pragma unroll
        for (int m = 0; m < MW; m++)
#pragma unroll
            for (int n = 0; n < NW; n++)
#pragma unroll
                for (int r = 0; r < 16; r++) lmax = fmaxf(lmax, fabsf(acc[m][n][r]));
#pragma unroll
        for (int off = 1; off < 64; off <<= 1) lmax = fmaxf(lmax, __shfl_xor(lmax, off, 64));
        __shared__ float smax[4];
        if (lane == 0) smax[wid] = lmax;
        __syncthreads();
        const float qmax = fmaxf(fmaxf(smax[wc], smax[wc + 2]), 1e-20f);
        const float sc = qmax * (1.f / 127.f);
        const float rsc = 127.f / qmax;
        if (lane == 0 && wr == 0) scq[blockIdx.x * 4 + blockIdx.y * 2 + wc] = sc;
#pragma unroll
        for (int m = 0; m < MW; m++)
#pragma unroll
            for (int n = 0; n < NW; n++)
#pragma unroll
                for (int r = 0; r < 16; r++) {
                    const int row = rowb + m * 32 + (r & 3) + 8 * (r >> 2);
                    if (row < N) {
                        int q = __float2int_rn(acc[m][n][r] * rsc) + 128;
                        q = min(255, max(0, q));
                        Zq[(size_t)row * COLS + colb + n * 32] = (unsigned char)q;
                    }
                }
    }

    const int hh = (c0 + wc * WN) >> 6;
    float asv[NW], adv[NW];
#pragma unroll
    for (int n = 0; n < NW; n++) {
        asv[n] = att_src[colb + n * 32];
        adv[n] = att_dst[colb + n * 32];
    }
#pragma unroll
    for (int m = 0; m < MW; m++)
#pragma unroll
        for (int r = 0; r < 16; r++) {
            const int row = rowb + m * 32 + (r & 3) + 8 * (r >> 2);
            float ps = 0.f, pd = 0.f;
#pragma unroll
            for (int n = 0; n < NW; n++) {
                ps = fmaf(acc[m][n][r], asv[n], ps);
                pd = fmaf(acc[m][n][r], adv[n], pd);
            }
#pragma unroll
            for (int off = 1; off < 32; off <<= 1) {
                ps += __shfl_xor(ps, off, 64);
                pd += __shfl_xor(pd, off, 64);
            }
            if ((lane & 31) == 0 && row < N) {
                As[(size_t)row * H + hh] = ps;
                Ad[(size_t)row * H + hh] = pd;
            }
        }
}

// ----------------------------- global max pool helpers -----------------------
__device__ __forceinline__ unsigned fenc(float f) {
    unsigned u = __float_as_uint(f);
    return (u & 0x80000000u) ? ~u : (u | 0x80000000u);
}

// ----------------------------- layer-1 aggregate (int8 z) --------------------
// One wave per node; head h = lane>>4 == column quarter. Scales folded in the
// preamble. LDS weights head-major PADDED [4][4][68]: the four head groups'
// b128 reads occupy disjoint bank quads (eliminates the R15 4-way conflict).
__global__ __launch_bounds__(256) void k_agg4(
    const unsigned char* __restrict__ Zq, const float* __restrict__ scq,
    const float* __restrict__ As, const float* __restrict__ Ad,
    const int* __restrict__ rowptr, const int* __restrict__ col,
    const float* __restrict__ bias, unsigned short* __restrict__ ohi, int N) {
    __shared__ float wlds[4][4][68];  // [wave][head][edge] (+4 pad: bank-disjoint)
    const int wv = threadIdx.x >> 6;
    const int n = blockIdx.x * 4 + wv;
    const int lane = threadIdx.x & 63;
    if (n >= N) return;
    const int h = lane >> 4;

    const int start = rowptr[n];
    const int total = rowptr[n + 1] - start;  // includes self-loop
    const int* __restrict__ cp = col + start;
    const float4 adn = *reinterpret_cast<const float4*>(Ad + (size_t)n * 4);
    const unsigned voff0 = (unsigned)lane * 4u;

    float a0 = 0.f, a1 = 0.f, a2 = 0.f, a3 = 0.f;
    float corr = 0.f;
    float4 dv = make_float4(0.f, 0.f, 0.f, 0.f);

    for (int base = 0; base < total; base += 64) {
        const int cnt = min(64, total - base);
        const int i = base + lane;
        int s = 0;
        float4 w = make_float4(0.f, 0.f, 0.f, 0.f);
        if (i < total) {
            s = cp[i];
            const float4 av = *reinterpret_cast<const float4*>(As + (size_t)s * 4);
            w.x = __expf(lrelu(av.x + adn.x));
            w.y = __expf(lrelu(av.y + adn.y));
            w.z = __expf(lrelu(av.z + adn.z));
            w.w = __expf(lrelu(av.w + adn.w));
        }
        dv.x += w.x; dv.y += w.y; dv.z += w.z; dv.w += w.w;
        if (i < total) {
            const float4 sc4 = *reinterpret_cast<const float4*>(scq + (size_t)(s >> 7) * 4);
            w.x *= sc4.x; w.y *= sc4.y; w.z *= sc4.z; w.w *= sc4.w;
        }
        wlds[wv][0][lane] = w.x;
        wlds[wv][1][lane] = w.y;
        wlds[wv][2][lane] = w.z;
        wlds[wv][3][lane] = w.w;

        int jj = 0;
        for (; jj + 8 <= cnt; jj += 8) {
            int sb[8];
            unsigned zb[8];
            const float4 wsa = *reinterpret_cast<const float4*>(&wlds[wv][h][jj]);
            const float4 wsb = *reinterpret_cast<const float4*>(&wlds[wv][h][jj + 4]);
#pragma unroll
            for (int u = 0; u < 8; u++) sb[u] = __builtin_amdgcn_readlane(s, jj + u);
#pragma unroll
            for (int u = 0; u < 8; u++)
                zb[u] = *reinterpret_cast<const unsigned*>(Zq + (((unsigned)sb[u] << 8) + voff0));
            const float ws[8] = {wsa.x, wsa.y, wsa.z, wsa.w, wsb.x, wsb.y, wsb.z, wsb.w};
#pragma unroll
            for (int u = 0; u < 8; u++) {
                a0 = fmaf(ws[u], (float)(zb[u] & 0xffu), a0);
                a1 = fmaf(ws[u], (float)((zb[u] >> 8) & 0xffu), a1);
                a2 = fmaf(ws[u], (float)((zb[u] >> 16) & 0xffu), a2);
                a3 = fmaf(ws[u], (float)(zb[u] >> 24), a3);
                corr += ws[u];
            }
        }
        for (; jj + 4 <= cnt; jj += 4) {
            int sb[4];
            unsigned zb[4];
            const float4 wsa = *reinterpret_cast<const float4*>(&wlds[wv][h][jj]);
#pragma unroll
            for (int u = 0; u < 4; u++) sb[u] = __builtin_amdgcn_readlane(s, jj + u);
#pragma unroll
            for (int u = 0; u < 4; u++)
                zb[u] = *reinterpret_cast<const unsigned*>(Zq + (((unsigned)sb[u] << 8) + voff0));
            const float ws[4] = {wsa.x, wsa.y, wsa.z, wsa.w};
#pragma unroll
            for (int u = 0; u < 4; u++) {
                a0 = fmaf(ws[u], (float)(zb[u] & 0xffu), a0);
                a1 = fmaf(ws[u], (float)((zb[u] >> 8) & 0xffu), a1);
                a2 = fmaf(ws[u], (float)((zb[u] >> 16) & 0xffu), a2);
                a3 = fmaf(ws[u], (float)(zb[u] >> 24), a3);
                corr += ws[u];
            }
        }
        for (; jj < cnt; jj++) {
            const int s0 = __builtin_amdgcn_readlane(s, jj);
            const float ws = wlds[wv][h][jj];
            const unsigned zb = *reinterpret_cast<const unsigned*>(Zq + (((unsigned)s0 << 8) + voff0));
            a0 = fmaf(ws, (float)(zb & 0xffu), a0);
            a1 = fmaf(ws, (float)((zb >> 8) & 0xffu), a1);
            a2 = fmaf(ws, (float)((zb >> 16) & 0xffu), a2);
            a3 = fmaf(ws, (float)(zb >> 24), a3);
            corr += ws;
        }
    }

    a0 -= 128.f * corr;
    a1 -= 128.f * corr;
    a2 -= 128.f * corr;
    a3 -= 128.f * corr;

#pragma unroll
    for (int off = 1; off < 64; off <<= 1) {
        dv.x += __shfl_xor(dv.x, off, 64);
        dv.y += __shfl_xor(dv.y, off, 64);
        dv.z += __shfl_xor(dv.z, off, 64);
        dv.w += __shfl_xor(dv.w, off, 64);
    }
    const float den = (h == 0) ? dv.x : (h == 1) ? dv.y : (h == 2) ? dv.z : dv.w;
    const float inv = 1.f / (den + 1e-16f);
    float o[4] = {a0, a1, a2, a3};
#pragma unroll
    for (int j = 0; j < 4; j++) {
        float ov = o[j] * inv + bias[lane * 4 + j];
        o[j] = (ov > 0.f) ? ov : expm1f(ov);
    }
    const ushort4 vh = make_ushort4(f2bf(o[0]), f2bf(o[1]), f2bf(o[2]), f2bf(o[3]));
    *reinterpret_cast<ushort4*>(ohi + (size_t)n * 256 + lane * 4) = vh;
}

// ----------------------------- layer-2 aggregate + pool ----------------------
__global__ __launch_bounds__(256) void k_agg1(
    const unsigned short* __restrict__ Zb, const float* __restrict__ As,
    const float* __restrict__ Ad, const int* __restrict__ rowptr,
    const int* __restrict__ col, const float* __restrict__ bias,
    const int* __restrict__ batch, unsigned* __restrict__ enc, int N) {
    const int n = blockIdx.x * 4 + (threadIdx.x >> 6);
    const int lane = threadIdx.x & 63;
    if (n >= N) return;

    const int start = rowptr[n];
    const int total = rowptr[n + 1] - start;  // includes self-loop
    const int* __restrict__ cp = col + start;
    const float adn = Ad[n];

    float acc = 0.f, denom = 0.f;

    for (int base = 0; base < total; base += 64) {
        const int cnt = min(64, total - base);
        const int i = base + lane;
        int s = 0;
        float w = 0.f;
        if (i < total) {
            s = cp[i];
            w = __expf(lrelu(As[s] + adn));
        }
        denom += w;

        int jj = 0;
        for (; jj + 8 <= cnt; jj += 8) {
            int sb[8];
            float wb[8], zb[8];
#pragma unroll
            for (int u = 0; u < 8; u++) {
                sb[u] = __builtin_amdgcn_readlane(s, jj + u);
                wb[u] = readlane_f(w, jj + u);
            }
#pragma unroll
            for (int u = 0; u < 8; u++) zb[u] = bf2f(Zb[(size_t)sb[u] * 64 + lane]);
#pragma unroll
            for (int u = 0; u < 8; u++) acc = fmaf(wb[u], zb[u], acc);
        }
        for (; jj < cnt; jj++) {
            const int s0 = __builtin_amdgcn_readlane(s, jj);
            const float w0 = readlane_f(w, jj);
            acc = fmaf(w0, bf2f(Zb[(size_t)s0 * 64 + lane]), acc);
        }
    }

#pragma unroll
    for (int off = 1; off < 64; off <<= 1) denom += __shfl_xor(denom, off, 64);

    const float ov = acc / (denom + 1e-16f) + bias[lane];
    const int g = batch[n];
    atomicMax(&enc[g * 64 + lane], fenc(ov));
}

__global__ void k_decode(const unsigned* __restrict__ enc, float* __restrict__ out, int M) {
    int id = blockIdx.x * 256 + threadIdx.x;
    if (id < M) {
        unsigned e = enc[id];
        unsigned u = (e & 0x80000000u) ? (e & 0x7FFFFFFFu) : ~e;
        out[id] = __uint_as_float(u);
    }
}

// ----------------------------- launch ---------------------------------------
extern "C" void kernel_launch(void* const* d_in, const int* in_sizes, int n_in,
                              void* d_out, int out_size, void* d_ws, size_t ws_size,
                              hipStream_t stream) {
    const float* x = (const float*)d_in[0];
    const int* edge_index = (const int*)d_in[1];
    const int* batch = (const int*)d_in[2];
    const float* W0 = (const float*)d_in[3];
    const float* as0 = (const float*)d_in[4];
    const float* ad0 = (const float*)d_in[5];
    const float* b0 = (const float*)d_in[6];
    const float* W1 = (const float*)d_in[7];
    const float* as1 = (const float*)d_in[8];
    const float* ad1 = (const float*)d_in[9];
    const float* b1 = (const float*)d_in[10];
    const float* W2 = (const float*)d_in[11];
    const float* as2 = (const float*)d_in[12];
    const float* ad2 = (const float*)d_in[13];
    const float* b2 = (const float*)d_in[14];

    const int N = in_sizes[0] / 64;  // nodes
    const int E = in_sizes[1] / 2;   // edges (no self-loops)
    const int G = out_size / 64;     // graphs
    const int Et = E + N;            // edges incl. self-loops
    const int nbk = (N + 63) >> 6;   // dst buckets

    const int* srcs = edge_index;
    const int* dsts = edge_index + E;

    char* p = (char*)d_ws;
    auto alloc = [&](size_t bytes) {
        void* r = (void*)p;
        p += (bytes + 255) & ~(size_t)255;
        return r;
    };
    unsigned short* Zb = (unsigned short*)alloc((size_t)N * 64 * 2);    // bf16 z (layer 2)
    unsigned char* Zq = (unsigned char*)alloc((size_t)N * 256);         // int8 z (layer 1)
    unsigned char* xq = (unsigned char*)alloc((size_t)N * 64);          // int8 x (layer 0)
    float* scl = (float*)alloc((size_t)N * 4);                          // x per-node scale
    unsigned short* Hb = (unsigned short*)alloc((size_t)N * 256 * 2);   // h0/h1 bf16
    unsigned short* Axhi = (unsigned short*)alloc((size_t)N * 256 * 2); // aggx hi
    unsigned short* Axlo = (unsigned short*)alloc((size_t)N * 256 * 2); // aggx lo
    float* As = (float*)alloc((size_t)N * 4 * 4);
    float* Ad = (float*)alloc((size_t)N * 4 * 4);
    int* deg = (int*)alloc((size_t)N * 4);
    int* bcnt = (int*)alloc(1024 * 4);  // contiguous with deg -> one memset
    int* incl = (int*)alloc((size_t)N * 4);
    int* bsum = (int*)alloc(1024 * 4);
    int* rowptr = (int*)alloc((size_t)(N + 1) * 4);
    int* cursor = (int*)alloc((size_t)N * 4);
    int* col = (int*)alloc((size_t)Et * 4);
    uint2* rec = (uint2*)alloc((size_t)Et * 8);
    int* bbase = (int*)alloc(1024 * 4);
    int* bcur = (int*)alloc(1024 * 4);
    unsigned short* wt0h = (unsigned short*)alloc(256 * 64 * 2);
    unsigned short* wt0l = (unsigned short*)alloc(256 * 64 * 2);
    unsigned short* wt1h = (unsigned short*)alloc(256 * 256 * 2);
    unsigned short* wt1l = (unsigned short*)alloc(256 * 256 * 2);
    unsigned short* wt2h = (unsigned short*)alloc(64 * 256 * 2);
    unsigned short* wt2l = (unsigned short*)alloc(64 * 256 * 2);
    float* vs0 = (float*)alloc(4 * 64 * 4);
    float* vd0 = (float*)alloc(4 * 64 * 4);
    const int gm = (N + 127) / 128;
    float* scq = (float*)alloc((size_t)gm * 4 * 4);
    unsigned* enc = (unsigned*)alloc((size_t)G * 64 * 4);

    hipMemsetAsync(deg, 0, (size_t)((char*)(bcnt + 1024) - (char*)deg), stream);

    const int nb = (N + 255) / 256;
    const int ab = (N + 3) / 4;
    const int hb = (Et + CH - 1) / CH;
    const int encb = (G * 64 + 255) / 256;

    // CSR build: hist -> scans -> bucketize -> place
    k_hist<<<hb, 256, 0, stream>>>(dsts, E, N, deg, bcnt);
    k_scan1<<<nb, 256, 0, stream>>>(deg, incl, bsum, N);
    k_scan2<<<2, 1024, 0, stream>>>(bsum, nb, bcnt, bbase, bcur, nbk);
    k_scan3<<<nb, 256, 0, stream>>>(deg, incl, bsum, rowptr, cursor, N, nb);
    k_bucket<<<hb, 256, 0, stream>>>(srcs, dsts, E, N, bcur, rec);
    k_place<<<(Et + 255) / 256, 256, 0, stream>>>(rec, Et, cursor, col);

    k_setup<<<385 + encb, 256, 0, stream>>>(W0, W1, W2, as0, ad0, wt0h, wt0l, wt1h, wt1l,
                                            wt2h, wt2l, vs0, vd0, enc, G * 64);

    // Layer 0: As0/Ad0 + int8 x; aggregate x (uint8 gather); post-GEMM
    k_att0<<<ab, 256, 0, stream>>>(x, vs0, vd0, As, Ad, xq, scl, N);
    k_aggx<<<ab, 256, 0, stream>>>(xq, scl, As, Ad, rowptr, col, Axhi, Axlo, N);
    k_gemm_pe<<<dim3(gm, 4), 256, 0, stream>>>(Axhi, Axlo, wt0h, wt0l, b0, Hb, N);

    // Layer 1: z GEMM (int8 out + per-quarter scales) + all-heads aggregate
    k_gemm_z<256, 256, 128, 128, 64, 1><<<dim3(gm, 2), 256, 0, stream>>>(
        Hb, wt1h, wt1l, as1, ad1, nullptr, Zq, scq, As, Ad, N);
    k_agg4<<<ab, 256, 0, stream>>>(Zq, scq, As, Ad, rowptr, col, b1, Hb, N);

    // Layer 2: z GEMM (bf16 out) + aggregate + fused pool
    k_gemm_z<256, 64, 128, 64, 64, 0><<<dim3(gm, 1), 256, 0, stream>>>(
        Hb, wt2h, wt2l, as2, ad2, Zb, nullptr, nullptr, As, Ad, N);
    k_agg1<<<ab, 256, 0, stream>>>(Zb, As, Ad, rowptr, col, b2, batch, enc, N);
    k_decode<<<(G * 64 + 255) / 256, 256, 0, stream>>>(enc, (float*)d_out, G * 64);
}

// Round 17
// 357.374 us; speedup vs baseline: 1.0049x; 1.0049x over previous
//
#include <hip/hip_runtime.h>
#include <math.h>

// ---------------------------------------------------------------------------
// GAT encoder: 3 GATConv layers (H=4,4,1) + ELU + global max pool.
// Layer 0: aggregate-then-project (bf16 x gather; latency-bound, int8 gather
//   measured as a regression) -> post-GEMM (bf16x3) -> h0 bf16.
// Layer 1: z-GEMM emits INT8 z (per-128x64-tile scale); aggregate gathers
//   uint8 at the XCD-compulsory fetch floor; scales folded into preamble
//   weights; head-major LDS weights padded [4][4][68] (conflict-free b128);
//   -128-bias corr accumulated in the PREAMBLE (gather-independent).
// Layer 2: z-GEMM bf16 out + aggregate + fused atomicMax pool.
// CSR build: bucketed counting sort (dense writes). 3-pass parallel scans.
// ---------------------------------------------------------------------------

typedef __attribute__((ext_vector_type(8))) short short8v;
typedef __attribute__((ext_vector_type(16))) float f32x16;

constexpr int CH = 4096;  // edges per bucketing block

__device__ __forceinline__ float lrelu(float x) { return x > 0.f ? x : 0.2f * x; }

__device__ __forceinline__ unsigned short f2bf(float x) {  // RNE
    unsigned u = __float_as_uint(x);
    return (unsigned short)((u + 0x7FFFu + ((u >> 16) & 1u)) >> 16);
}
__device__ __forceinline__ float bf2f(unsigned short h) {
    return __uint_as_float(((unsigned)h) << 16);
}
__device__ __forceinline__ float readlane_f(float v, int l) {
    return __uint_as_float((unsigned)__builtin_amdgcn_readlane((int)__float_as_uint(v), l));
}

// ----------------------------- CSR build (bucketed) --------------------------
__global__ __launch_bounds__(256) void k_hist(const int* __restrict__ dst, int E, int N,
                                              int* __restrict__ deg, int* __restrict__ bcnt) {
    __shared__ int h[1024];
    for (int b = threadIdx.x; b < 1024; b += 256) h[b] = 0;
    __syncthreads();
    const int base = blockIdx.x * CH;
    const int Et = E + N;
    for (int i = threadIdx.x; i < CH; i += 256) {
        const int e = base + i;
        if (e < Et) {
            const int d = (e < E) ? dst[e] : (e - E);
            atomicAdd(&deg[d], 1);
            atomicAdd(&h[d >> 6], 1);
        }
    }
    __syncthreads();
    for (int b = threadIdx.x; b < 1024; b += 256)
        if (h[b]) atomicAdd(&bcnt[b], h[b]);
}

__global__ __launch_bounds__(256) void k_scan1(const int* __restrict__ deg,
                                               int* __restrict__ incl,
                                               int* __restrict__ bsum, int N) {
    const int i = blockIdx.x * 256 + threadIdx.x;
    const int lane = threadIdx.x & 63;
    const int wv = threadIdx.x >> 6;
    int sc = (i < N) ? deg[i] : 0;
#pragma unroll
    for (int off = 1; off < 64; off <<= 1) {
        int t = __shfl_up(sc, off, 64);
        if (lane >= off) sc += t;
    }
    __shared__ int wsum[4];
    if (lane == 63) wsum[wv] = sc;
    __syncthreads();
    int woff = 0;
#pragma unroll
    for (int k = 0; k < 3; k++)
        if (wv > k) woff += wsum[k];
    sc += woff;
    if (i < N) incl[i] = sc;
    if (threadIdx.x == 255) bsum[blockIdx.x] = sc;
}

__global__ __launch_bounds__(1024) void k_scan2(int* __restrict__ bsum, int nb,
                                                const int* __restrict__ bcnt,
                                                int* __restrict__ bbase,
                                                int* __restrict__ bcur, int nbk) {
    const int t = threadIdx.x;
    const int lane = t & 63;
    const int wv = t >> 6;
    const bool nodeScan = (blockIdx.x == 0);
    const int cnt = nodeScan ? nb : nbk;
    int v = 0;
    if (t < cnt) v = nodeScan ? bsum[t] : bcnt[t];
    int sc = v;
#pragma unroll
    for (int off = 1; off < 64; off <<= 1) {
        int u = __shfl_up(sc, off, 64);
        if (lane >= off) sc += u;
    }
    __shared__ int wsum[16];
    if (lane == 63) wsum[wv] = sc;
    __syncthreads();
    int woff = 0;
#pragma unroll
    for (int k = 0; k < 15; k++)
        if (wv > k) woff += wsum[k];
    sc += woff;
    if (t < cnt) {
        if (nodeScan) {
            bsum[t] = sc;
        } else {
            bbase[t] = sc - v;
            bcur[t] = sc - v;
        }
    }
}

__global__ void k_scan3(const int* __restrict__ deg, const int* __restrict__ incl,
                        const int* __restrict__ bsum, int* __restrict__ rowptr,
                        int* __restrict__ cursor, int N, int nb) {
    int i = blockIdx.x * 256 + threadIdx.x;
    if (i < N) {
        const int off = (blockIdx.x > 0) ? bsum[blockIdx.x - 1] : 0;
        const int excl = incl[i] + off - deg[i];
        rowptr[i] = excl;
        cursor[i] = excl;
        if (i == N - 1) rowptr[N] = bsum[nb - 1];
    }
}

__global__ __launch_bounds__(256) void k_bucket(const int* __restrict__ src,
                                                const int* __restrict__ dst, int E, int N,
                                                int* __restrict__ bcur,
                                                uint2* __restrict__ rec) {
    __shared__ int h[1024];
    __shared__ int boff[1024];
    for (int b = threadIdx.x; b < 1024; b += 256) h[b] = 0;
    __syncthreads();
    const int base = blockIdx.x * CH;
    const int Et = E + N;
    for (int i = threadIdx.x; i < CH; i += 256) {
        const int e = base + i;
        if (e < Et) {
            const int d = (e < E) ? dst[e] : (e - E);
            atomicAdd(&h[d >> 6], 1);
        }
    }
    __syncthreads();
    for (int b = threadIdx.x; b < 1024; b += 256)
        boff[b] = h[b] ? atomicAdd(&bcur[b], h[b]) : 0;
    __syncthreads();
    for (int b = threadIdx.x; b < 1024; b += 256) h[b] = 0;
    __syncthreads();
    for (int i = threadIdx.x; i < CH; i += 256) {
        const int e = base + i;
        if (e < Et) {
            int d, s;
            if (e < E) {
                d = dst[e];
                s = src[e];
            } else {
                d = e - E;
                s = d;
            }
            const int r = atomicAdd(&h[d >> 6], 1);
            rec[boff[d >> 6] + r] = make_uint2((unsigned)s, (unsigned)d);
        }
    }
}

__global__ void k_place(const uint2* __restrict__ rec, int Et, int* __restrict__ cursor,
                        int* __restrict__ col) {
    int e = blockIdx.x * 256 + threadIdx.x;
    if (e < Et) {
        const uint2 rd = rec[e];
        const int p = atomicAdd(&cursor[(int)rd.y], 1);
        col[p] = (int)rd.x;
    }
}

// ----------------------------- fused setup -----------------------------------
__global__ void k_setup(const float* __restrict__ W0, const float* __restrict__ W1,
                        const float* __restrict__ W2, const float* __restrict__ as0,
                        const float* __restrict__ ad0,
                        unsigned short* __restrict__ wt0h, unsigned short* __restrict__ wt0l,
                        unsigned short* __restrict__ wt1h, unsigned short* __restrict__ wt1l,
                        unsigned short* __restrict__ wt2h, unsigned short* __restrict__ wt2l,
                        float* __restrict__ vs0, float* __restrict__ vd0,
                        unsigned* __restrict__ enc, int encM) {
    const int b = blockIdx.x;
    const int t = threadIdx.x;
    if (b < 64) {
        const int i = b * 256 + t;
        const int c = i / 64, k = i % 64;
        const float xw = W0[(size_t)k * 256 + c];
        const unsigned short h = f2bf(xw);
        wt0h[i] = h;
        wt0l[i] = f2bf(xw - bf2f(h));
    } else if (b < 320) {
        const int i = (b - 64) * 256 + t;
        const int c = i / 256, k = i % 256;
        const float xw = W1[(size_t)k * 256 + c];
        const unsigned short h = f2bf(xw);
        wt1h[i] = h;
        wt1l[i] = f2bf(xw - bf2f(h));
    } else if (b < 384) {
        const int i = (b - 320) * 256 + t;
        const int c = i / 256, k = i % 256;
        const float xw = W2[(size_t)k * 64 + c];
        const unsigned short h = f2bf(xw);
        wt2h[i] = h;
        wt2l[i] = f2bf(xw - bf2f(h));
    } else if (b == 384) {
        const int k = t;
        if (k < 64) {
            for (int h = 0; h < 4; h++) {
                float s = 0.f, d = 0.f;
                for (int c = 0; c < 64; c++) {
                    float w = W0[(size_t)k * 256 + h * 64 + c];
                    s = fmaf(w, as0[h * 64 + c], s);
                    d = fmaf(w, ad0[h * 64 + c], d);
                }
                vs0[h * 64 + k] = s;
                vd0[h * 64 + k] = d;
            }
        }
    } else {
        const int i = (b - 385) * 256 + t;
        if (i < encM) enc[i] = 0u;
    }
}

// As0/Ad0 (wave per node); also emits bf16 copy of x.
__global__ __launch_bounds__(256) void k_att0(
    const float* __restrict__ X, const float* __restrict__ vs, const float* __restrict__ vd,
    float* __restrict__ As, float* __restrict__ Ad, unsigned short* __restrict__ xb, int N) {
    const int n = blockIdx.x * 4 + (threadIdx.x >> 6);
    const int lane = threadIdx.x & 63;
    if (n >= N) return;
    const float xv = X[(size_t)n * 64 + lane];
    xb[(size_t)n * 64 + lane] = f2bf(xv);
#pragma unroll
    for (int h = 0; h < 4; h++) {
        float ps = xv * vs[h * 64 + lane];
        float pd = xv * vd[h * 64 + lane];
#pragma unroll
        for (int off = 1; off < 64; off <<= 1) {
            ps += __shfl_xor(ps, off, 64);
            pd += __shfl_xor(pd, off, 64);
        }
        if (lane == 0) {
            As[(size_t)n * 4 + h] = ps;
            Ad[(size_t)n * 4 + h] = pd;
        }
    }
}

// ----------------------------- layer-0 x-aggregate (bf16) --------------------
// Wave per node, lane = x-dim. 128B/edge bf16 gather serves all 4 heads.
// Weights via LDS transpose; denominators per-lane preamble + wave reduce.
__global__ __launch_bounds__(256) void k_aggx(
    const unsigned short* __restrict__ Xb, const float* __restrict__ As,
    const float* __restrict__ Ad, const int* __restrict__ rowptr,
    const int* __restrict__ col, unsigned short* __restrict__ ohi,
    unsigned short* __restrict__ olo, int N) {
    __shared__ float wlds[4][64][4];
    const int wv = threadIdx.x >> 6;
    const int n = blockIdx.x * 4 + wv;
    const int lane = threadIdx.x & 63;
    if (n >= N) return;

    const int start = rowptr[n];
    const int total = rowptr[n + 1] - start;  // includes self-loop
    const int* __restrict__ cp = col + start;
    const float4 adn = *reinterpret_cast<const float4*>(Ad + (size_t)n * 4);

    float a0 = 0.f, a1 = 0.f, a2 = 0.f, a3 = 0.f;
    float4 dv = make_float4(0.f, 0.f, 0.f, 0.f);

    for (int base = 0; base < total; base += 64) {
        const int cnt = min(64, total - base);
        const int i = base + lane;
        int s = 0;
        float4 w = make_float4(0.f, 0.f, 0.f, 0.f);
        if (i < total) {
            s = cp[i];
            const float4 av = *reinterpret_cast<const float4*>(As + (size_t)s * 4);
            w.x = __expf(lrelu(av.x + adn.x));
            w.y = __expf(lrelu(av.y + adn.y));
            w.z = __expf(lrelu(av.z + adn.z));
            w.w = __expf(lrelu(av.w + adn.w));
        }
        dv.x += w.x; dv.y += w.y; dv.z += w.z; dv.w += w.w;
        *reinterpret_cast<float4*>(&wlds[wv][lane][0]) = w;

        int jj = 0;
        for (; jj + 4 <= cnt; jj += 4) {
            int sb[4];
            float4 wj[4];
            float xv[4];
#pragma unroll
            for (int u = 0; u < 4; u++) {
                sb[u] = __builtin_amdgcn_readlane(s, jj + u);
                wj[u] = *reinterpret_cast<const float4*>(&wlds[wv][jj + u][0]);
            }
#pragma unroll
            for (int u = 0; u < 4; u++) xv[u] = bf2f(Xb[(size_t)sb[u] * 64 + lane]);
#pragma unroll
            for (int u = 0; u < 4; u++) {
                a0 = fmaf(wj[u].x, xv[u], a0);
                a1 = fmaf(wj[u].y, xv[u], a1);
                a2 = fmaf(wj[u].z, xv[u], a2);
                a3 = fmaf(wj[u].w, xv[u], a3);
            }
        }
        for (; jj < cnt; jj++) {
            const int s0 = __builtin_amdgcn_readlane(s, jj);
            const float4 wj = *reinterpret_cast<const float4*>(&wlds[wv][jj][0]);
            const float xv = bf2f(Xb[(size_t)s0 * 64 + lane]);
            a0 = fmaf(wj.x, xv, a0);
            a1 = fmaf(wj.y, xv, a1);
            a2 = fmaf(wj.z, xv, a2);
            a3 = fmaf(wj.w, xv, a3);
        }
    }

#pragma unroll
    for (int off = 1; off < 64; off <<= 1) {
        dv.x += __shfl_xor(dv.x, off, 64);
        dv.y += __shfl_xor(dv.y, off, 64);
        dv.z += __shfl_xor(dv.z, off, 64);
        dv.w += __shfl_xor(dv.w, off, 64);
    }

    const float o[4] = {a0 / (dv.x + 1e-16f), a1 / (dv.y + 1e-16f),
                        a2 / (dv.z + 1e-16f), a3 / (dv.w + 1e-16f)};
#pragma unroll
    for (int h = 0; h < 4; h++) {
        const unsigned short hb = f2bf(o[h]);
        ohi[(size_t)n * 256 + h * 64 + lane] = hb;
        olo[(size_t)n * 256 + h * 64 + lane] = f2bf(o[h] - bf2f(hb));
    }
}

// ----------------------------- post-GEMM (layer 0) ---------------------------
__global__ __launch_bounds__(256) void k_gemm_pe(
    const unsigned short* __restrict__ Ahi, const unsigned short* __restrict__ Alo,
    const unsigned short* __restrict__ Bhi, const unsigned short* __restrict__ Blo,
    const float* __restrict__ bias, unsigned short* __restrict__ Ohi, int N) {
    constexpr int LD = 40, BM = 128, K = 64;
    __shared__ unsigned short sa[2][BM * LD];
    __shared__ unsigned short sb[2][64 * LD];

    const int tid = threadIdx.x;
    const int n0 = blockIdx.x * BM;
    const int hh = blockIdx.y;
    const int wid = tid >> 6, lane = tid & 63;

    const unsigned short* __restrict__ Ah = Ahi + hh * 64;
    const unsigned short* __restrict__ Al = Alo + hh * 64;
    const unsigned short* __restrict__ Bh = Bhi + hh * 64 * K;
    const unsigned short* __restrict__ Bl = Blo + hh * 64 * K;

    f32x16 acc[2];
#pragma unroll
    for (int n = 0; n < 2; n++)
#pragma unroll
        for (int i = 0; i < 16; i++) acc[n][i] = 0.f;

    const int srow = tid >> 2, schk = tid & 3;

    for (int kb = 0; kb < K; kb += 32) {
        __syncthreads();
#pragma unroll
        for (int rr = 0; rr < 2; rr++) {
            const int r = srow + rr * 64;
            const int row = n0 + r;
            short8v vh = {0, 0, 0, 0, 0, 0, 0, 0}, vl = {0, 0, 0, 0, 0, 0, 0, 0};
            if (row < N) {
                vh = *reinterpret_cast<const short8v*>(Ah + (size_t)row * 256 + kb + schk * 8);
                vl = *reinterpret_cast<const short8v*>(Al + (size_t)row * 256 + kb + schk * 8);
            }
            *reinterpret_cast<short8v*>(&sa[0][r * LD + schk * 8]) = vh;
            *reinterpret_cast<short8v*>(&sa[1][r * LD + schk * 8]) = vl;
        }
        {
            const short8v vh =
                *reinterpret_cast<const short8v*>(Bh + (size_t)srow * K + kb + schk * 8);
            const short8v vl =
                *reinterpret_cast<const short8v*>(Bl + (size_t)srow * K + kb + schk * 8);
            *reinterpret_cast<short8v*>(&sb[0][srow * LD + schk * 8]) = vh;
            *reinterpret_cast<short8v*>(&sb[1][srow * LD + schk * 8]) = vl;
        }
        __syncthreads();
#pragma unroll
        for (int ks = 0; ks < 2; ks++) {
            const int koff = ks * 16 + (lane >> 5) * 8;
            const int ar = wid * 32 + (lane & 31);
            const short8v ah = *reinterpret_cast<const short8v*>(&sa[0][ar * LD + koff]);
            const short8v al = *reinterpret_cast<const short8v*>(&sa[1][ar * LD + koff]);
            short8v bh[2], bl[2];
#pragma unroll
            for (int n = 0; n < 2; n++) {
                const int br = n * 32 + (lane & 31);
                bh[n] = *reinterpret_cast<const short8v*>(&sb[0][br * LD + koff]);
                bl[n] = *reinterpret_cast<const short8v*>(&sb[1][br * LD + koff]);
            }
#pragma unroll
            for (int n = 0; n < 2; n++) {
                acc[n] = __builtin_amdgcn_mfma_f32_32x32x16_bf16(ah, bh[n], acc[n], 0, 0, 0);
                acc[n] = __builtin_amdgcn_mfma_f32_32x32x16_bf16(ah, bl[n], acc[n], 0, 0, 0);
                acc[n] = __builtin_amdgcn_mfma_f32_32x32x16_bf16(al, bh[n], acc[n], 0, 0, 0);
            }
        }
    }

    const int rowb = n0 + wid * 32 + 4 * (lane >> 5);
#pragma unroll
    for (int n = 0; n < 2; n++) {
        const int c = (lane & 31) + n * 32;
        const float bv = bias[hh * 64 + c];
#pragma unroll
        for (int r = 0; r < 16; r++) {
            const int row = rowb + (r & 3) + 8 * (r >> 2);
            if (row < N) {
                float ov = acc[n][r] + bv;
                ov = (ov > 0.f) ? ov : expm1f(ov);
                Ohi[(size_t)row * 256 + hh * 64 + c] = f2bf(ov);
            }
        }
    }
}

// ----------------------------- z GEMM (layers 1,2) ---------------------------
template <int K, int COLS, int BM, int BN, int WN, int OUTMODE>
__global__ __launch_bounds__(256) void k_gemm_z(
    const unsigned short* __restrict__ Ahi,
    const unsigned short* __restrict__ Bhi, const unsigned short* __restrict__ Blo,
    const float* __restrict__ att_src, const float* __restrict__ att_dst,
    unsigned short* __restrict__ Zb, unsigned char* __restrict__ Zq,
    float* __restrict__ scq, float* __restrict__ As, float* __restrict__ Ad, int N) {
    constexpr int LD = 40;
    constexpr int WAVES_N = BN / WN;
    constexpr int WAVES_M = 4 / WAVES_N;
    constexpr int WM = BM / WAVES_M;
    constexpr int MW = WM / 32, NW = WN / 32;
    constexpr int H = COLS / 64;
    __shared__ unsigned short sa[BM * LD];
    __shared__ unsigned short sb[2][BN * LD];

    const int tid = threadIdx.x;
    const int n0 = blockIdx.x * BM;
    const int c0 = blockIdx.y * BN;
    const int wid = tid >> 6, lane = tid & 63;
    const int wr = wid / WAVES_N, wc = wid % WAVES_N;

    f32x16 acc[MW][NW];
#pragma unroll
    for (int m = 0; m < MW; m++)
#pragma unroll
        for (int n = 0; n < NW; n++)
#pragma unroll
            for (int i = 0; i < 16; i++) acc[m][n][i] = 0.f;

    const int srow = tid >> 2, schk = tid & 3;

    for (int kb = 0; kb < K; kb += 32) {
        __syncthreads();
#pragma unroll
        for (int rr = 0; rr < BM / 64; rr++) {
            const int r = srow + rr * 64;
            const int row = n0 + r;
            short8v vh = {0, 0, 0, 0, 0, 0, 0, 0};
            if (row < N)
                vh = *reinterpret_cast<const short8v*>(Ahi + (size_t)row * K + kb + schk * 8);
            *reinterpret_cast<short8v*>(&sa[r * LD + schk * 8]) = vh;
        }
#pragma unroll
        for (int rr = 0; rr < BN / 64; rr++) {
            const int cc = srow + rr * 64;
            const short8v vh =
                *reinterpret_cast<const short8v*>(Bhi + (size_t)(c0 + cc) * K + kb + schk * 8);
            const short8v vl =
                *reinterpret_cast<const short8v*>(Blo + (size_t)(c0 + cc) * K + kb + schk * 8);
            *reinterpret_cast<short8v*>(&sb[0][cc * LD + schk * 8]) = vh;
            *reinterpret_cast<short8v*>(&sb[1][cc * LD + schk * 8]) = vl;
        }
        __syncthreads();
#pragma unroll
        for (int ks = 0; ks < 2; ks++) {
            const int koff = ks * 16 + (lane >> 5) * 8;
            short8v ah[MW], bh[NW], bl[NW];
#pragma unroll
            for (int m = 0; m < MW; m++) {
                const int ar = wr * WM + m * 32 + (lane & 31);
                ah[m] = *reinterpret_cast<const short8v*>(&sa[ar * LD + koff]);
            }
#pragma unroll
            for (int n = 0; n < NW; n++) {
                const int br = wc * WN + n * 32 + (lane & 31);
                bh[n] = *reinterpret_cast<const short8v*>(&sb[0][br * LD + koff]);
                bl[n] = *reinterpret_cast<const short8v*>(&sb[1][br * LD + koff]);
            }
#pragma unroll
            for (int m = 0; m < MW; m++)
#pragma unroll
                for (int n = 0; n < NW; n++) {
                    acc[m][n] = __builtin_amdgcn_mfma_f32_32x32x16_bf16(ah[m], bh[n], acc[m][n], 0, 0, 0);
                    acc[m][n] = __builtin_amdgcn_mfma_f32_32x32x16_bf16(ah[m], bl[n], acc[m][n], 0, 0, 0);
                }
        }
    }

    const int colb = c0 + wc * WN + (lane & 31);
    const int rowb = n0 + wr * WM + 4 * (lane >> 5);

    if constexpr (OUTMODE == 0) {
#pragma unroll
        for (int m = 0; m < MW; m++)
#pragma unroll
            for (int n = 0; n < NW; n++)
#pragma unroll
                for (int r = 0; r < 16; r++) {
                    const int row = rowb + m * 32 + (r & 3) + 8 * (r >> 2);
                    if (row < N) Zb[(size_t)row * COLS + colb + n * 32] = f2bf(acc[m][n][r]);
                }
    } else {
        float lmax = 0.f;
#pragma unroll
        for (int m = 0; m < MW; m++)
#pragma unroll
            for (int n = 0; n < NW; n++)
#pragma unroll
                for (int r = 0; r < 16; r++) lmax = fmaxf(lmax, fabsf(acc[m][n][r]));
#pragma unroll
        for (int off = 1; off < 64; off <<= 1) lmax = fmaxf(lmax, __shfl_xor(lmax, off, 64));
        __shared__ float smax[4];
        if (lane == 0) smax[wid] = lmax;
        __syncthreads();
        const float qmax = fmaxf(fmaxf(smax[wc], smax[wc + 2]), 1e-20f);
        const float sc = qmax * (1.f / 127.f);
        const float rsc = 127.f / qmax;
        if (lane == 0 && wr == 0) scq[blockIdx.x * 4 + blockIdx.y * 2 + wc] = sc;
#pragma unroll
        for (int m = 0; m < MW; m++)
#pragma unroll
            for (int n = 0; n < NW; n++)
#pragma unroll
                for (int r = 0; r < 16; r++) {
                    const int row = rowb + m * 32 + (r & 3) + 8 * (r >> 2);
                    if (row < N) {
                        int q = __float2int_rn(acc[m][n][r] * rsc) + 128;
                        q = min(255, max(0, q));
                        Zq[(size_t)row * COLS + colb + n * 32] = (unsigned char)q;
                    }
                }
    }

    const int hh = (c0 + wc * WN) >> 6;
    float asv[NW], adv[NW];
#pragma unroll
    for (int n = 0; n < NW; n++) {
        asv[n] = att_src[colb + n * 32];
        adv[n] = att_dst[colb + n * 32];
    }
#pragma unroll
    for (int m = 0; m < MW; m++)
#pragma unroll
        for (int r = 0; r < 16; r++) {
            const int row = rowb + m * 32 + (r & 3) + 8 * (r >> 2);
            float ps = 0.f, pd = 0.f;
#pragma unroll
            for (int n = 0; n < NW; n++) {
                ps = fmaf(acc[m][n][r], asv[n], ps);
                pd = fmaf(acc[m][n][r], adv[n], pd);
            }
#pragma unroll
            for (int off = 1; off < 32; off <<= 1) {
                ps += __shfl_xor(ps, off, 64);
                pd += __shfl_xor(pd, off, 64);
            }
            if ((lane & 31) == 0 && row < N) {
                As[(size_t)row * H + hh] = ps;
                Ad[(size_t)row * H + hh] = pd;
            }
        }
}

// ----------------------------- global max pool helpers -----------------------
__device__ __forceinline__ unsigned fenc(float f) {
    unsigned u = __float_as_uint(f);
    return (u & 0x80000000u) ? ~u : (u | 0x80000000u);
}

// ----------------------------- layer-1 aggregate (int8 z) --------------------
// One wave per node; head h = lane>>4 == column quarter. Scales folded in the
// preamble; -128-bias corr ALSO accumulated in the preamble (per-lane float4,
// wave-reduced, selected by head) -> the hot loop is readlane + load + 4 fma.
// LDS weights head-major padded [4][4][68] (bank-conflict-free b128 reads).
__global__ __launch_bounds__(256) void k_agg4(
    const unsigned char* __restrict__ Zq, const float* __restrict__ scq,
    const float* __restrict__ As, const float* __restrict__ Ad,
    const int* __restrict__ rowptr, const int* __restrict__ col,
    const float* __restrict__ bias, unsigned short* __restrict__ ohi, int N) {
    __shared__ float wlds[4][4][68];  // [wave][head][edge] (+4 pad: bank-disjoint)
    const int wv = threadIdx.x >> 6;
    const int n = blockIdx.x * 4 + wv;
    const int lane = threadIdx.x & 63;
    if (n >= N) return;
    const int h = lane >> 4;

    const int start = rowptr[n];
    const int total = rowptr[n + 1] - start;  // includes self-loop
    const int* __restrict__ cp = col + start;
    const float4 adn = *reinterpret_cast<const float4*>(Ad + (size_t)n * 4);
    const unsigned voff0 = (unsigned)lane * 4u;

    float a0 = 0.f, a1 = 0.f, a2 = 0.f, a3 = 0.f;
    float4 dv = make_float4(0.f, 0.f, 0.f, 0.f);
    float4 cr = make_float4(0.f, 0.f, 0.f, 0.f);

    for (int base = 0; base < total; base += 64) {
        const int cnt = min(64, total - base);
        const int i = base + lane;
        int s = 0;
        float4 w = make_float4(0.f, 0.f, 0.f, 0.f);
        if (i < total) {
            s = cp[i];
            const float4 av = *reinterpret_cast<const float4*>(As + (size_t)s * 4);
            w.x = __expf(lrelu(av.x + adn.x));
            w.y = __expf(lrelu(av.y + adn.y));
            w.z = __expf(lrelu(av.z + adn.z));
            w.w = __expf(lrelu(av.w + adn.w));
        }
        dv.x += w.x; dv.y += w.y; dv.z += w.z; dv.w += w.w;
        if (i < total) {
            const float4 sc4 = *reinterpret_cast<const float4*>(scq + (size_t)(s >> 7) * 4);
            w.x *= sc4.x; w.y *= sc4.y; w.z *= sc4.z; w.w *= sc4.w;
        }
        cr.x += w.x; cr.y += w.y; cr.z += w.z; cr.w += w.w;
        wlds[wv][0][lane] = w.x;
        wlds[wv][1][lane] = w.y;
        wlds[wv][2][lane] = w.z;
        wlds[wv][3][lane] = w.w;

        int jj = 0;
        for (; jj + 8 <= cnt; jj += 8) {
            int sb[8];
            unsigned zb[8];
            const float4 wsa = *reinterpret_cast<const float4*>(&wlds[wv][h][jj]);
            const float4 wsb = *reinterpret_cast<const float4*>(&wlds[wv][h][jj + 4]);
#pragma unroll
            for (int u = 0; u < 8; u++) sb[u] = __builtin_amdgcn_readlane(s, jj + u);
#pragma unroll
            for (int u = 0; u < 8; u++)
                zb[u] = *reinterpret_cast<const unsigned*>(Zq + (((unsigned)sb[u] << 8) + voff0));
            const float ws[8] = {wsa.x, wsa.y, wsa.z, wsa.w, wsb.x, wsb.y, wsb.z, wsb.w};
#pragma unroll
            for (int u = 0; u < 8; u++) {
                a0 = fmaf(ws[u], (float)(zb[u] & 0xffu), a0);
                a1 = fmaf(ws[u], (float)((zb[u] >> 8) & 0xffu), a1);
                a2 = fmaf(ws[u], (float)((zb[u] >> 16) & 0xffu), a2);
                a3 = fmaf(ws[u], (float)(zb[u] >> 24), a3);
            }
        }
        for (; jj + 4 <= cnt; jj += 4) {
            int sb[4];
            unsigned zb[4];
            const float4 wsa = *reinterpret_cast<const float4*>(&wlds[wv][h][jj]);
#pragma unroll
            for (int u = 0; u < 4; u++) sb[u] = __builtin_amdgcn_readlane(s, jj + u);
#pragma unroll
            for (int u = 0; u < 4; u++)
                zb[u] = *reinterpret_cast<const unsigned*>(Zq + (((unsigned)sb[u] << 8) + voff0));
            const float ws[4] = {wsa.x, wsa.y, wsa.z, wsa.w};
#pragma unroll
            for (int u = 0; u < 4; u++) {
                a0 = fmaf(ws[u], (float)(zb[u] & 0xffu), a0);
                a1 = fmaf(ws[u], (float)((zb[u] >> 8) & 0xffu), a1);
                a2 = fmaf(ws[u], (float)((zb[u] >> 16) & 0xffu), a2);
                a3 = fmaf(ws[u], (float)(zb[u] >> 24), a3);
            }
        }
        for (; jj < cnt; jj++) {
            const int s0 = __builtin_amdgcn_readlane(s, jj);
            const float ws = wlds[wv][h][jj];
            const unsigned zb = *reinterpret_cast<const unsigned*>(Zq + (((unsigned)s0 << 8) + voff0));
            a0 = fmaf(ws, (float)(zb & 0xffu), a0);
            a1 = fmaf(ws, (float)((zb >> 8) & 0xffu), a1);
            a2 = fmaf(ws, (float)((zb >> 16) & 0xffu), a2);
            a3 = fmaf(ws, (float)(zb >> 24), a3);
        }
    }

#pragma unroll
    for (int off = 1; off < 64; off <<= 1) {
        dv.x += __shfl_xor(dv.x, off, 64);
        dv.y += __shfl_xor(dv.y, off, 64);
        dv.z += __shfl_xor(dv.z, off, 64);
        dv.w += __shfl_xor(dv.w, off, 64);
        cr.x += __shfl_xor(cr.x, off, 64);
        cr.y += __shfl_xor(cr.y, off, 64);
        cr.z += __shfl_xor(cr.z, off, 64);
        cr.w += __shfl_xor(cr.w, off, 64);
    }
    const float den = (h == 0) ? dv.x : (h == 1) ? dv.y : (h == 2) ? dv.z : dv.w;
    const float corr = (h == 0) ? cr.x : (h == 1) ? cr.y : (h == 2) ? cr.z : cr.w;
    a0 -= 128.f * corr;
    a1 -= 128.f * corr;
    a2 -= 128.f * corr;
    a3 -= 128.f * corr;
    const float inv = 1.f / (den + 1e-16f);
    float o[4] = {a0, a1, a2, a3};
#pragma unroll
    for (int j = 0; j < 4; j++) {
        float ov = o[j] * inv + bias[lane * 4 + j];
        o[j] = (ov > 0.f) ? ov : expm1f(ov);
    }
    const ushort4 vh = make_ushort4(f2bf(o[0]), f2bf(o[1]), f2bf(o[2]), f2bf(o[3]));
    *reinterpret_cast<ushort4*>(ohi + (size_t)n * 256 + lane * 4) = vh;
}

// ----------------------------- layer-2 aggregate + pool ----------------------
__global__ __launch_bounds__(256) void k_agg1(
    const unsigned short* __restrict__ Zb, const float* __restrict__ As,
    const float* __restrict__ Ad, const int* __restrict__ rowptr,
    const int* __restrict__ col, const float* __restrict__ bias,
    const int* __restrict__ batch, unsigned* __restrict__ enc, int N) {
    const int n = blockIdx.x * 4 + (threadIdx.x >> 6);
    const int lane = threadIdx.x & 63;
    if (n >= N) return;

    const int start = rowptr[n];
    const int total = rowptr[n + 1] - start;  // includes self-loop
    const int* __restrict__ cp = col + start;
    const float adn = Ad[n];

    float acc = 0.f, denom = 0.f;

    for (int base = 0; base < total; base += 64) {
        const int cnt = min(64, total - base);
        const int i = base + lane;
        int s = 0;
        float w = 0.f;
        if (i < total) {
            s = cp[i];
            w = __expf(lrelu(As[s] + adn));
        }
        denom += w;

        int jj = 0;
        for (; jj + 8 <= cnt; jj += 8) {
            int sb[8];
            float wb[8], zb[8];
#pragma unroll
            for (int u = 0; u < 8; u++) {
                sb[u] = __builtin_amdgcn_readlane(s, jj + u);
                wb[u] = readlane_f(w, jj + u);
            }
#pragma unroll
            for (int u = 0; u < 8; u++) zb[u] = bf2f(Zb[(size_t)sb[u] * 64 + lane]);
#pragma unroll
            for (int u = 0; u < 8; u++) acc = fmaf(wb[u], zb[u], acc);
        }
        for (; jj < cnt; jj++) {
            const int s0 = __builtin_amdgcn_readlane(s, jj);
            const float w0 = readlane_f(w, jj);
            acc = fmaf(w0, bf2f(Zb[(size_t)s0 * 64 + lane]), acc);
        }
    }

#pragma unroll
    for (int off = 1; off < 64; off <<= 1) denom += __shfl_xor(denom, off, 64);

    const float ov = acc / (denom + 1e-16f) + bias[lane];
    const int g = batch[n];
    atomicMax(&enc[g * 64 + lane], fenc(ov));
}

__global__ void k_decode(const unsigned* __restrict__ enc, float* __restrict__ out, int M) {
    int id = blockIdx.x * 256 + threadIdx.x;
    if (id < M) {
        unsigned e = enc[id];
        unsigned u = (e & 0x80000000u) ? (e & 0x7FFFFFFFu) : ~e;
        out[id] = __uint_as_float(u);
    }
}

// ----------------------------- launch ---------------------------------------
extern "C" void kernel_launch(void* const* d_in, const int* in_sizes, int n_in,
                              void* d_out, int out_size, void* d_ws, size_t ws_size,
                              hipStream_t stream) {
    const float* x = (const float*)d_in[0];
    const int* edge_index = (const int*)d_in[1];
    const int* batch = (const int*)d_in[2];
    const float* W0 = (const float*)d_in[3];
    const float* as0 = (const float*)d_in[4];
    const float* ad0 = (const float*)d_in[5];
    const float* b0 = (const float*)d_in[6];
    const float* W1 = (const float*)d_in[7];
    const float* as1 = (const float*)d_in[8];
    const float* ad1 = (const float*)d_in[9];
    const float* b1 = (const float*)d_in[10];
    const float* W2 = (const float*)d_in[11];
    const float* as2 = (const float*)d_in[12];
    const float* ad2 = (const float*)d_in[13];
    const float* b2 = (const float*)d_in[14];

    const int N = in_sizes[0] / 64;  // nodes
    const int E = in_sizes[1] / 2;   // edges (no self-loops)
    const int G = out_size / 64;     // graphs
    const int Et = E + N;            // edges incl. self-loops
    const int nbk = (N + 63) >> 6;   // dst buckets

    const int* srcs = edge_index;
    const int* dsts = edge_index + E;

    char* p = (char*)d_ws;
    auto alloc = [&](size_t bytes) {
        void* r = (void*)p;
        p += (bytes + 255) & ~(size_t)255;
        return r;
    };
    unsigned short* Zb = (unsigned short*)alloc((size_t)N * 64 * 2);    // bf16 z (layer 2)
    unsigned char* Zq = (unsigned char*)alloc((size_t)N * 256);         // int8 z (layer 1)
    unsigned short* xb = (unsigned short*)alloc((size_t)N * 64 * 2);    // bf16 x (layer 0)
    unsigned short* Hb = (unsigned short*)alloc((size_t)N * 256 * 2);   // h0/h1 bf16
    unsigned short* Axhi = (unsigned short*)alloc((size_t)N * 256 * 2); // aggx hi
    unsigned short* Axlo = (unsigned short*)alloc((size_t)N * 256 * 2); // aggx lo
    float* As = (float*)alloc((size_t)N * 4 * 4);
    float* Ad = (float*)alloc((size_t)N * 4 * 4);
    int* deg = (int*)alloc((size_t)N * 4);
    int* bcnt = (int*)alloc(1024 * 4);  // contiguous with deg -> one memset
    int* incl = (int*)alloc((size_t)N * 4);
    int* bsum = (int*)alloc(1024 * 4);
    int* rowptr = (int*)alloc((size_t)(N + 1) * 4);
    int* cursor = (int*)alloc((size_t)N * 4);
    int* col = (int*)alloc((size_t)Et * 4);
    uint2* rec = (uint2*)alloc((size_t)Et * 8);
    int* bbase = (int*)alloc(1024 * 4);
    int* bcur = (int*)alloc(1024 * 4);
    unsigned short* wt0h = (unsigned short*)alloc(256 * 64 * 2);
    unsigned short* wt0l = (unsigned short*)alloc(256 * 64 * 2);
    unsigned short* wt1h = (unsigned short*)alloc(256 * 256 * 2);
    unsigned short* wt1l = (unsigned short*)alloc(256 * 256 * 2);
    unsigned short* wt2h = (unsigned short*)alloc(64 * 256 * 2);
    unsigned short* wt2l = (unsigned short*)alloc(64 * 256 * 2);
    float* vs0 = (float*)alloc(4 * 64 * 4);
    float* vd0 = (float*)alloc(4 * 64 * 4);
    const int gm = (N + 127) / 128;
    float* scq = (float*)alloc((size_t)gm * 4 * 4);
    unsigned* enc = (unsigned*)alloc((size_t)G * 64 * 4);

    hipMemsetAsync(deg, 0, (size_t)((char*)(bcnt + 1024) - (char*)deg), stream);

    const int nb = (N + 255) / 256;
    const int ab = (N + 3) / 4;
    const int hb = (Et + CH - 1) / CH;
    const int encb = (G * 64 + 255) / 256;

    // CSR build: hist -> scans -> bucketize -> place
    k_hist<<<hb, 256, 0, stream>>>(dsts, E, N, deg, bcnt);
    k_scan1<<<nb, 256, 0, stream>>>(deg, incl, bsum, N);
    k_scan2<<<2, 1024, 0, stream>>>(bsum, nb, bcnt, bbase, bcur, nbk);
    k_scan3<<<nb, 256, 0, stream>>>(deg, incl, bsum, rowptr, cursor, N, nb);
    k_bucket<<<hb, 256, 0, stream>>>(srcs, dsts, E, N, bcur, rec);
    k_place<<<(Et + 255) / 256, 256, 0, stream>>>(rec, Et, cursor, col);

    k_setup<<<385 + encb, 256, 0, stream>>>(W0, W1, W2, as0, ad0, wt0h, wt0l, wt1h, wt1l,
                                            wt2h, wt2l, vs0, vd0, enc, G * 64);

    // Layer 0: As0/Ad0 + bf16 x copy; aggregate x (bf16 gather); post-GEMM
    k_att0<<<ab, 256, 0, stream>>>(x, vs0, vd0, As, Ad, xb, N);
    k_aggx<<<ab, 256, 0, stream>>>(xb, As, Ad, rowptr, col, Axhi, Axlo, N);
    k_gemm_pe<<<dim3(gm, 4), 256, 0, stream>>>(Axhi, Axlo, wt0h, wt0l, b0, Hb, N);

    // Layer 1: z GEMM (int8 out + per-quarter scales) + all-heads aggregate
    k_gemm_z<256, 256, 128, 128, 64, 1><<<dim3(gm, 2), 256, 0, stream>>>(
        Hb, wt1h, wt1l, as1, ad1, nullptr, Zq, scq, As, Ad, N);
    k_agg4<<<ab, 256, 0, stream>>>(Zq, scq, As, Ad, rowptr, col, b1, Hb, N);

    // Layer 2: z GEMM (bf16 out) + aggregate + fused pool
    k_gemm_z<256, 64, 128, 64, 64, 0><<<dim3(gm, 1), 256, 0, stream>>>(
        Hb, wt2h, wt2l, as2, ad2, Zb, nullptr, nullptr, As, Ad, N);
    k_agg1<<<ab, 256, 0, stream>>>(Zb, As, Ad, rowptr, col, b2, batch, enc, N);
    k_decode<<<(G * 64 + 255) / 256, 256, 0, stream>>>(enc, (float*)d_out, G * 64);
}

// Round 18
// 349.458 us; speedup vs baseline: 1.0277x; 1.0227x over previous
//
#include <hip/hip_runtime.h>
#include <math.h>

// ---------------------------------------------------------------------------
// GAT encoder: 3 GATConv layers (H=4,4,1) + ELU + global max pool.
// Best-measured composition (A/B across R10-R17):
// Layer 0: aggregate-then-project, bf16 x gather (int8 gather measured as a
//   regression: latency-bound, not fetch-bound) -> post-GEMM (bf16x3).
// Layer 1: z-GEMM emits INT8 z (per-128x64-tile scale); aggregate gathers
//   uint8 at the XCD-compulsory fetch floor; scales folded into preamble
//   weights; head-major LDS weights padded [4][4][68] (conflict-free b128);
//   corr accumulated IN the hot loop (preamble hoist measured -10us: +4 VGPR
//   cost occupancy 53->44%).
// Layer 2: z-GEMM bf16 out + aggregate + fused atomicMax pool.
// CSR build: bucketed counting sort (dense writes). 3-pass parallel scans.
// ---------------------------------------------------------------------------

typedef __attribute__((ext_vector_type(8))) short short8v;
typedef __attribute__((ext_vector_type(16))) float f32x16;

constexpr int CH = 4096;  // edges per bucketing block

__device__ __forceinline__ float lrelu(float x) { return x > 0.f ? x : 0.2f * x; }

__device__ __forceinline__ unsigned short f2bf(float x) {  // RNE
    unsigned u = __float_as_uint(x);
    return (unsigned short)((u + 0x7FFFu + ((u >> 16) & 1u)) >> 16);
}
__device__ __forceinline__ float bf2f(unsigned short h) {
    return __uint_as_float(((unsigned)h) << 16);
}
__device__ __forceinline__ float readlane_f(float v, int l) {
    return __uint_as_float((unsigned)__builtin_amdgcn_readlane((int)__float_as_uint(v), l));
}

// ----------------------------- CSR build (bucketed) --------------------------
__global__ __launch_bounds__(256) void k_hist(const int* __restrict__ dst, int E, int N,
                                              int* __restrict__ deg, int* __restrict__ bcnt) {
    __shared__ int h[1024];
    for (int b = threadIdx.x; b < 1024; b += 256) h[b] = 0;
    __syncthreads();
    const int base = blockIdx.x * CH;
    const int Et = E + N;
    for (int i = threadIdx.x; i < CH; i += 256) {
        const int e = base + i;
        if (e < Et) {
            const int d = (e < E) ? dst[e] : (e - E);
            atomicAdd(&deg[d], 1);
            atomicAdd(&h[d >> 6], 1);
        }
    }
    __syncthreads();
    for (int b = threadIdx.x; b < 1024; b += 256)
        if (h[b]) atomicAdd(&bcnt[b], h[b]);
}

__global__ __launch_bounds__(256) void k_scan1(const int* __restrict__ deg,
                                               int* __restrict__ incl,
                                               int* __restrict__ bsum, int N) {
    const int i = blockIdx.x * 256 + threadIdx.x;
    const int lane = threadIdx.x & 63;
    const int wv = threadIdx.x >> 6;
    int sc = (i < N) ? deg[i] : 0;
#pragma unroll
    for (int off = 1; off < 64; off <<= 1) {
        int t = __shfl_up(sc, off, 64);
        if (lane >= off) sc += t;
    }
    __shared__ int wsum[4];
    if (lane == 63) wsum[wv] = sc;
    __syncthreads();
    int woff = 0;
#pragma unroll
    for (int k = 0; k < 3; k++)
        if (wv > k) woff += wsum[k];
    sc += woff;
    if (i < N) incl[i] = sc;
    if (threadIdx.x == 255) bsum[blockIdx.x] = sc;
}

__global__ __launch_bounds__(1024) void k_scan2(int* __restrict__ bsum, int nb,
                                                const int* __restrict__ bcnt,
                                                int* __restrict__ bbase,
                                                int* __restrict__ bcur, int nbk) {
    const int t = threadIdx.x;
    const int lane = t & 63;
    const int wv = t >> 6;
    const bool nodeScan = (blockIdx.x == 0);
    const int cnt = nodeScan ? nb : nbk;
    int v = 0;
    if (t < cnt) v = nodeScan ? bsum[t] : bcnt[t];
    int sc = v;
#pragma unroll
    for (int off = 1; off < 64; off <<= 1) {
        int u = __shfl_up(sc, off, 64);
        if (lane >= off) sc += u;
    }
    __shared__ int wsum[16];
    if (lane == 63) wsum[wv] = sc;
    __syncthreads();
    int woff = 0;
#pragma unroll
    for (int k = 0; k < 15; k++)
        if (wv > k) woff += wsum[k];
    sc += woff;
    if (t < cnt) {
        if (nodeScan) {
            bsum[t] = sc;
        } else {
            bbase[t] = sc - v;
            bcur[t] = sc - v;
        }
    }
}

__global__ void k_scan3(const int* __restrict__ deg, const int* __restrict__ incl,
                        const int* __restrict__ bsum, int* __restrict__ rowptr,
                        int* __restrict__ cursor, int N, int nb) {
    int i = blockIdx.x * 256 + threadIdx.x;
    if (i < N) {
        const int off = (blockIdx.x > 0) ? bsum[blockIdx.x - 1] : 0;
        const int excl = incl[i] + off - deg[i];
        rowptr[i] = excl;
        cursor[i] = excl;
        if (i == N - 1) rowptr[N] = bsum[nb - 1];
    }
}

__global__ __launch_bounds__(256) void k_bucket(const int* __restrict__ src,
                                                const int* __restrict__ dst, int E, int N,
                                                int* __restrict__ bcur,
                                                uint2* __restrict__ rec) {
    __shared__ int h[1024];
    __shared__ int boff[1024];
    for (int b = threadIdx.x; b < 1024; b += 256) h[b] = 0;
    __syncthreads();
    const int base = blockIdx.x * CH;
    const int Et = E + N;
    for (int i = threadIdx.x; i < CH; i += 256) {
        const int e = base + i;
        if (e < Et) {
            const int d = (e < E) ? dst[e] : (e - E);
            atomicAdd(&h[d >> 6], 1);
        }
    }
    __syncthreads();
    for (int b = threadIdx.x; b < 1024; b += 256)
        boff[b] = h[b] ? atomicAdd(&bcur[b], h[b]) : 0;
    __syncthreads();
    for (int b = threadIdx.x; b < 1024; b += 256) h[b] = 0;
    __syncthreads();
    for (int i = threadIdx.x; i < CH; i += 256) {
        const int e = base + i;
        if (e < Et) {
            int d, s;
            if (e < E) {
                d = dst[e];
                s = src[e];
            } else {
                d = e - E;
                s = d;
            }
            const int r = atomicAdd(&h[d >> 6], 1);
            rec[boff[d >> 6] + r] = make_uint2((unsigned)s, (unsigned)d);
        }
    }
}

__global__ void k_place(const uint2* __restrict__ rec, int Et, int* __restrict__ cursor,
                        int* __restrict__ col) {
    int e = blockIdx.x * 256 + threadIdx.x;
    if (e < Et) {
        const uint2 rd = rec[e];
        const int p = atomicAdd(&cursor[(int)rd.y], 1);
        col[p] = (int)rd.x;
    }
}

// ----------------------------- fused setup -----------------------------------
__global__ void k_setup(const float* __restrict__ W0, const float* __restrict__ W1,
                        const float* __restrict__ W2, const float* __restrict__ as0,
                        const float* __restrict__ ad0,
                        unsigned short* __restrict__ wt0h, unsigned short* __restrict__ wt0l,
                        unsigned short* __restrict__ wt1h, unsigned short* __restrict__ wt1l,
                        unsigned short* __restrict__ wt2h, unsigned short* __restrict__ wt2l,
                        float* __restrict__ vs0, float* __restrict__ vd0,
                        unsigned* __restrict__ enc, int encM) {
    const int b = blockIdx.x;
    const int t = threadIdx.x;
    if (b < 64) {
        const int i = b * 256 + t;
        const int c = i / 64, k = i % 64;
        const float xw = W0[(size_t)k * 256 + c];
        const unsigned short h = f2bf(xw);
        wt0h[i] = h;
        wt0l[i] = f2bf(xw - bf2f(h));
    } else if (b < 320) {
        const int i = (b - 64) * 256 + t;
        const int c = i / 256, k = i % 256;
        const float xw = W1[(size_t)k * 256 + c];
        const unsigned short h = f2bf(xw);
        wt1h[i] = h;
        wt1l[i] = f2bf(xw - bf2f(h));
    } else if (b < 384) {
        const int i = (b - 320) * 256 + t;
        const int c = i / 256, k = i % 256;
        const float xw = W2[(size_t)k * 64 + c];
        const unsigned short h = f2bf(xw);
        wt2h[i] = h;
        wt2l[i] = f2bf(xw - bf2f(h));
    } else if (b == 384) {
        const int k = t;
        if (k < 64) {
            for (int h = 0; h < 4; h++) {
                float s = 0.f, d = 0.f;
                for (int c = 0; c < 64; c++) {
                    float w = W0[(size_t)k * 256 + h * 64 + c];
                    s = fmaf(w, as0[h * 64 + c], s);
                    d = fmaf(w, ad0[h * 64 + c], d);
                }
                vs0[h * 64 + k] = s;
                vd0[h * 64 + k] = d;
            }
        }
    } else {
        const int i = (b - 385) * 256 + t;
        if (i < encM) enc[i] = 0u;
    }
}

// As0/Ad0 (wave per node); also emits bf16 copy of x.
__global__ __launch_bounds__(256) void k_att0(
    const float* __restrict__ X, const float* __restrict__ vs, const float* __restrict__ vd,
    float* __restrict__ As, float* __restrict__ Ad, unsigned short* __restrict__ xb, int N) {
    const int n = blockIdx.x * 4 + (threadIdx.x >> 6);
    const int lane = threadIdx.x & 63;
    if (n >= N) return;
    const float xv = X[(size_t)n * 64 + lane];
    xb[(size_t)n * 64 + lane] = f2bf(xv);
#pragma unroll
    for (int h = 0; h < 4; h++) {
        float ps = xv * vs[h * 64 + lane];
        float pd = xv * vd[h * 64 + lane];
#pragma unroll
        for (int off = 1; off < 64; off <<= 1) {
            ps += __shfl_xor(ps, off, 64);
            pd += __shfl_xor(pd, off, 64);
        }
        if (lane == 0) {
            As[(size_t)n * 4 + h] = ps;
            Ad[(size_t)n * 4 + h] = pd;
        }
    }
}

// ----------------------------- layer-0 x-aggregate (bf16) --------------------
__global__ __launch_bounds__(256) void k_aggx(
    const unsigned short* __restrict__ Xb, const float* __restrict__ As,
    const float* __restrict__ Ad, const int* __restrict__ rowptr,
    const int* __restrict__ col, unsigned short* __restrict__ ohi,
    unsigned short* __restrict__ olo, int N) {
    __shared__ float wlds[4][64][4];
    const int wv = threadIdx.x >> 6;
    const int n = blockIdx.x * 4 + wv;
    const int lane = threadIdx.x & 63;
    if (n >= N) return;

    const int start = rowptr[n];
    const int total = rowptr[n + 1] - start;  // includes self-loop
    const int* __restrict__ cp = col + start;
    const float4 adn = *reinterpret_cast<const float4*>(Ad + (size_t)n * 4);

    float a0 = 0.f, a1 = 0.f, a2 = 0.f, a3 = 0.f;
    float4 dv = make_float4(0.f, 0.f, 0.f, 0.f);

    for (int base = 0; base < total; base += 64) {
        const int cnt = min(64, total - base);
        const int i = base + lane;
        int s = 0;
        float4 w = make_float4(0.f, 0.f, 0.f, 0.f);
        if (i < total) {
            s = cp[i];
            const float4 av = *reinterpret_cast<const float4*>(As + (size_t)s * 4);
            w.x = __expf(lrelu(av.x + adn.x));
            w.y = __expf(lrelu(av.y + adn.y));
            w.z = __expf(lrelu(av.z + adn.z));
            w.w = __expf(lrelu(av.w + adn.w));
        }
        dv.x += w.x; dv.y += w.y; dv.z += w.z; dv.w += w.w;
        *reinterpret_cast<float4*>(&wlds[wv][lane][0]) = w;

        int jj = 0;
        for (; jj + 4 <= cnt; jj += 4) {
            int sb[4];
            float4 wj[4];
            float xv[4];
#pragma unroll
            for (int u = 0; u < 4; u++) {
                sb[u] = __builtin_amdgcn_readlane(s, jj + u);
                wj[u] = *reinterpret_cast<const float4*>(&wlds[wv][jj + u][0]);
            }
#pragma unroll
            for (int u = 0; u < 4; u++) xv[u] = bf2f(Xb[(size_t)sb[u] * 64 + lane]);
#pragma unroll
            for (int u = 0; u < 4; u++) {
                a0 = fmaf(wj[u].x, xv[u], a0);
                a1 = fmaf(wj[u].y, xv[u], a1);
                a2 = fmaf(wj[u].z, xv[u], a2);
                a3 = fmaf(wj[u].w, xv[u], a3);
            }
        }
        for (; jj < cnt; jj++) {
            const int s0 = __builtin_amdgcn_readlane(s, jj);
            const float4 wj = *reinterpret_cast<const float4*>(&wlds[wv][jj][0]);
            const float xv = bf2f(Xb[(size_t)s0 * 64 + lane]);
            a0 = fmaf(wj.x, xv, a0);
            a1 = fmaf(wj.y, xv, a1);
            a2 = fmaf(wj.z, xv, a2);
            a3 = fmaf(wj.w, xv, a3);
        }
    }

#pragma unroll
    for (int off = 1; off < 64; off <<= 1) {
        dv.x += __shfl_xor(dv.x, off, 64);
        dv.y += __shfl_xor(dv.y, off, 64);
        dv.z += __shfl_xor(dv.z, off, 64);
        dv.w += __shfl_xor(dv.w, off, 64);
    }

    const float o[4] = {a0 / (dv.x + 1e-16f), a1 / (dv.y + 1e-16f),
                        a2 / (dv.z + 1e-16f), a3 / (dv.w + 1e-16f)};
#pragma unroll
    for (int h = 0; h < 4; h++) {
        const unsigned short hb = f2bf(o[h]);
        ohi[(size_t)n * 256 + h * 64 + lane] = hb;
        olo[(size_t)n * 256 + h * 64 + lane] = f2bf(o[h] - bf2f(hb));
    }
}

// ----------------------------- post-GEMM (layer 0) ---------------------------
__global__ __launch_bounds__(256) void k_gemm_pe(
    const unsigned short* __restrict__ Ahi, const unsigned short* __restrict__ Alo,
    const unsigned short* __restrict__ Bhi, const unsigned short* __restrict__ Blo,
    const float* __restrict__ bias, unsigned short* __restrict__ Ohi, int N) {
    constexpr int LD = 40, BM = 128, K = 64;
    __shared__ unsigned short sa[2][BM * LD];
    __shared__ unsigned short sb[2][64 * LD];

    const int tid = threadIdx.x;
    const int n0 = blockIdx.x * BM;
    const int hh = blockIdx.y;
    const int wid = tid >> 6, lane = tid & 63;

    const unsigned short* __restrict__ Ah = Ahi + hh * 64;
    const unsigned short* __restrict__ Al = Alo + hh * 64;
    const unsigned short* __restrict__ Bh = Bhi + hh * 64 * K;
    const unsigned short* __restrict__ Bl = Blo + hh * 64 * K;

    f32x16 acc[2];
#pragma unroll
    for (int n = 0; n < 2; n++)
#pragma unroll
        for (int i = 0; i < 16; i++) acc[n][i] = 0.f;

    const int srow = tid >> 2, schk = tid & 3;

    for (int kb = 0; kb < K; kb += 32) {
        __syncthreads();
#pragma unroll
        for (int rr = 0; rr < 2; rr++) {
            const int r = srow + rr * 64;
            const int row = n0 + r;
            short8v vh = {0, 0, 0, 0, 0, 0, 0, 0}, vl = {0, 0, 0, 0, 0, 0, 0, 0};
            if (row < N) {
                vh = *reinterpret_cast<const short8v*>(Ah + (size_t)row * 256 + kb + schk * 8);
                vl = *reinterpret_cast<const short8v*>(Al + (size_t)row * 256 + kb + schk * 8);
            }
            *reinterpret_cast<short8v*>(&sa[0][r * LD + schk * 8]) = vh;
            *reinterpret_cast<short8v*>(&sa[1][r * LD + schk * 8]) = vl;
        }
        {
            const short8v vh =
                *reinterpret_cast<const short8v*>(Bh + (size_t)srow * K + kb + schk * 8);
            const short8v vl =
                *reinterpret_cast<const short8v*>(Bl + (size_t)srow * K + kb + schk * 8);
            *reinterpret_cast<short8v*>(&sb[0][srow * LD + schk * 8]) = vh;
            *reinterpret_cast<short8v*>(&sb[1][srow * LD + schk * 8]) = vl;
        }
        __syncthreads();
#pragma unroll
        for (int ks = 0; ks < 2; ks++) {
            const int koff = ks * 16 + (lane >> 5) * 8;
            const int ar = wid * 32 + (lane & 31);
            const short8v ah = *reinterpret_cast<const short8v*>(&sa[0][ar * LD + koff]);
            const short8v al = *reinterpret_cast<const short8v*>(&sa[1][ar * LD + koff]);
            short8v bh[2], bl[2];
#pragma unroll
            for (int n = 0; n < 2; n++) {
                const int br = n * 32 + (lane & 31);
                bh[n] = *reinterpret_cast<const short8v*>(&sb[0][br * LD + koff]);
                bl[n] = *reinterpret_cast<const short8v*>(&sb[1][br * LD + koff]);
            }
#pragma unroll
            for (int n = 0; n < 2; n++) {
                acc[n] = __builtin_amdgcn_mfma_f32_32x32x16_bf16(ah, bh[n], acc[n], 0, 0, 0);
                acc[n] = __builtin_amdgcn_mfma_f32_32x32x16_bf16(ah, bl[n], acc[n], 0, 0, 0);
                acc[n] = __builtin_amdgcn_mfma_f32_32x32x16_bf16(al, bh[n], acc[n], 0, 0, 0);
            }
        }
    }

    const int rowb = n0 + wid * 32 + 4 * (lane >> 5);
#pragma unroll
    for (int n = 0; n < 2; n++) {
        const int c = (lane & 31) + n * 32;
        const float bv = bias[hh * 64 + c];
#pragma unroll
        for (int r = 0; r < 16; r++) {
            const int row = rowb + (r & 3) + 8 * (r >> 2);
            if (row < N) {
                float ov = acc[n][r] + bv;
                ov = (ov > 0.f) ? ov : expm1f(ov);
                Ohi[(size_t)row * 256 + hh * 64 + c] = f2bf(ov);
            }
        }
    }
}

// ----------------------------- z GEMM (layers 1,2) ---------------------------
template <int K, int COLS, int BM, int BN, int WN, int OUTMODE>
__global__ __launch_bounds__(256) void k_gemm_z(
    const unsigned short* __restrict__ Ahi,
    const unsigned short* __restrict__ Bhi, const unsigned short* __restrict__ Blo,
    const float* __restrict__ att_src, const float* __restrict__ att_dst,
    unsigned short* __restrict__ Zb, unsigned char* __restrict__ Zq,
    float* __restrict__ scq, float* __restrict__ As, float* __restrict__ Ad, int N) {
    constexpr int LD = 40;
    constexpr int WAVES_N = BN / WN;
    constexpr int WAVES_M = 4 / WAVES_N;
    constexpr int WM = BM / WAVES_M;
    constexpr int MW = WM / 32, NW = WN / 32;
    constexpr int H = COLS / 64;
    __shared__ unsigned short sa[BM * LD];
    __shared__ unsigned short sb[2][BN * LD];

    const int tid = threadIdx.x;
    const int n0 = blockIdx.x * BM;
    const int c0 = blockIdx.y * BN;
    const int wid = tid >> 6, lane = tid & 63;
    const int wr = wid / WAVES_N, wc = wid % WAVES_N;

    f32x16 acc[MW][NW];
#pragma unroll
    for (int m = 0; m < MW; m++)
#pragma unroll
        for (int n = 0; n < NW; n++)
#pragma unroll
            for (int i = 0; i < 16; i++) acc[m][n][i] = 0.f;

    const int srow = tid >> 2, schk = tid & 3;

    for (int kb = 0; kb < K; kb += 32) {
        __syncthreads();
#pragma unroll
        for (int rr = 0; rr < BM / 64; rr++) {
            const int r = srow + rr * 64;
            const int row = n0 + r;
            short8v vh = {0, 0, 0, 0, 0, 0, 0, 0};
            if (row < N)
                vh = *reinterpret_cast<const short8v*>(Ahi + (size_t)row * K + kb + schk * 8);
            *reinterpret_cast<short8v*>(&sa[r * LD + schk * 8]) = vh;
        }
#pragma unroll
        for (int rr = 0; rr < BN / 64; rr++) {
            const int cc = srow + rr * 64;
            const short8v vh =
                *reinterpret_cast<const short8v*>(Bhi + (size_t)(c0 + cc) * K + kb + schk * 8);
            const short8v vl =
                *reinterpret_cast<const short8v*>(Blo + (size_t)(c0 + cc) * K + kb + schk * 8);
            *reinterpret_cast<short8v*>(&sb[0][cc * LD + schk * 8]) = vh;
            *reinterpret_cast<short8v*>(&sb[1][cc * LD + schk * 8]) = vl;
        }
        __syncthreads();
#pragma unroll
        for (int ks = 0; ks < 2; ks++) {
            const int koff = ks * 16 + (lane >> 5) * 8;
            short8v ah[MW], bh[NW], bl[NW];
#pragma unroll
            for (int m = 0; m < MW; m++) {
                const int ar = wr * WM + m * 32 + (lane & 31);
                ah[m] = *reinterpret_cast<const short8v*>(&sa[ar * LD + koff]);
            }
#pragma unroll
            for (int n = 0; n < NW; n++) {
                const int br = wc * WN + n * 32 + (lane & 31);
                bh[n] = *reinterpret_cast<const short8v*>(&sb[0][br * LD + koff]);
                bl[n] = *reinterpret_cast<const short8v*>(&sb[1][br * LD + koff]);
            }
#pragma unroll
            for (int m = 0; m < MW; m++)
#pragma unroll
                for (int n = 0; n < NW; n++) {
                    acc[m][n] = __builtin_amdgcn_mfma_f32_32x32x16_bf16(ah[m], bh[n], acc[m][n], 0, 0, 0);
                    acc[m][n] = __builtin_amdgcn_mfma_f32_32x32x16_bf16(ah[m], bl[n], acc[m][n], 0, 0, 0);
                }
        }
    }

    const int colb = c0 + wc * WN + (lane & 31);
    const int rowb = n0 + wr * WM + 4 * (lane >> 5);

    if constexpr (OUTMODE == 0) {
#pragma unroll
        for (int m = 0; m < MW; m++)
#pragma unroll
            for (int n = 0; n < NW; n++)
#pragma unroll
                for (int r = 0; r < 16; r++) {
                    const int row = rowb + m * 32 + (r & 3) + 8 * (r >> 2);
                    if (row < N) Zb[(size_t)row * COLS + colb + n * 32] = f2bf(acc[m][n][r]);
                }
    } else {
        float lmax = 0.f;
#pragma unroll
        for (int m = 0; m < MW; m++)
#pragma unroll
            for (int n = 0; n < NW; n++)
#pragma unroll
                for (int r = 0; r < 16; r++) lmax = fmaxf(lmax, fabsf(acc[m][n][r]));
#pragma unroll
        for (int off = 1; off < 64; off <<= 1) lmax = fmaxf(lmax, __shfl_xor(lmax, off, 64));
        __shared__ float smax[4];
        if (lane == 0) smax[wid] = lmax;
        __syncthreads();
        const float qmax = fmaxf(fmaxf(smax[wc], smax[wc + 2]), 1e-20f);
        const float sc = qmax * (1.f / 127.f);
        const float rsc = 127.f / qmax;
        if (lane == 0 && wr == 0) scq[blockIdx.x * 4 + blockIdx.y * 2 + wc] = sc;
#pragma unroll
        for (int m = 0; m < MW; m++)
#pragma unroll
            for (int n = 0; n < NW; n++)
#pragma unroll
                for (int r = 0; r < 16; r++) {
                    const int row = rowb + m * 32 + (r & 3) + 8 * (r >> 2);
                    if (row < N) {
                        int q = __float2int_rn(acc[m][n][r] * rsc) + 128;
                        q = min(255, max(0, q));
                        Zq[(size_t)row * COLS + colb + n * 32] = (unsigned char)q;
                    }
                }
    }

    const int hh = (c0 + wc * WN) >> 6;
    float asv[NW], adv[NW];
#pragma unroll
    for (int n = 0; n < NW; n++) {
        asv[n] = att_src[colb + n * 32];
        adv[n] = att_dst[colb + n * 32];
    }
#pragma unroll
    for (int m = 0; m < MW; m++)
#pragma unroll
        for (int r = 0; r < 16; r++) {
            const int row = rowb + m * 32 + (r & 3) + 8 * (r >> 2);
            float ps = 0.f, pd = 0.f;
#pragma unroll
            for (int n = 0; n < NW; n++) {
                ps = fmaf(acc[m][n][r], asv[n], ps);
                pd = fmaf(acc[m][n][r], adv[n], pd);
            }
#pragma unroll
            for (int off = 1; off < 32; off <<= 1) {
                ps += __shfl_xor(ps, off, 64);
                pd += __shfl_xor(pd, off, 64);
            }
            if ((lane & 31) == 0 && row < N) {
                As[(size_t)row * H + hh] = ps;
                Ad[(size_t)row * H + hh] = pd;
            }
        }
}

// ----------------------------- global max pool helpers -----------------------
__device__ __forceinline__ unsigned fenc(float f) {
    unsigned u = __float_as_uint(f);
    return (u & 0x80000000u) ? ~u : (u | 0x80000000u);
}

// ----------------------------- layer-1 aggregate (int8 z) --------------------
// One wave per node; head h = lane>>4 == column quarter. Scales folded in the
// preamble; corr accumulated in the hot loop (40 VGPR, best measured
// occupancy). LDS weights head-major padded [4][4][68] (conflict-free b128).
__global__ __launch_bounds__(256) void k_agg4(
    const unsigned char* __restrict__ Zq, const float* __restrict__ scq,
    const float* __restrict__ As, const float* __restrict__ Ad,
    const int* __restrict__ rowptr, const int* __restrict__ col,
    const float* __restrict__ bias, unsigned short* __restrict__ ohi, int N) {
    __shared__ float wlds[4][4][68];  // [wave][head][edge] (+4 pad: bank-disjoint)
    const int wv = threadIdx.x >> 6;
    const int n = blockIdx.x * 4 + wv;
    const int lane = threadIdx.x & 63;
    if (n >= N) return;
    const int h = lane >> 4;

    const int start = rowptr[n];
    const int total = rowptr[n + 1] - start;  // includes self-loop
    const int* __restrict__ cp = col + start;
    const float4 adn = *reinterpret_cast<const float4*>(Ad + (size_t)n * 4);
    const unsigned voff0 = (unsigned)lane * 4u;

    float a0 = 0.f, a1 = 0.f, a2 = 0.f, a3 = 0.f;
    float corr = 0.f;
    float4 dv = make_float4(0.f, 0.f, 0.f, 0.f);

    for (int base = 0; base < total; base += 64) {
        const int cnt = min(64, total - base);
        const int i = base + lane;
        int s = 0;
        float4 w = make_float4(0.f, 0.f, 0.f, 0.f);
        if (i < total) {
            s = cp[i];
            const float4 av = *reinterpret_cast<const float4*>(As + (size_t)s * 4);
            w.x = __expf(lrelu(av.x + adn.x));
            w.y = __expf(lrelu(av.y + adn.y));
            w.z = __expf(lrelu(av.z + adn.z));
            w.w = __expf(lrelu(av.w + adn.w));
        }
        dv.x += w.x; dv.y += w.y; dv.z += w.z; dv.w += w.w;
        if (i < total) {
            const float4 sc4 = *reinterpret_cast<const float4*>(scq + (size_t)(s >> 7) * 4);
            w.x *= sc4.x; w.y *= sc4.y; w.z *= sc4.z; w.w *= sc4.w;
        }
        wlds[wv][0][lane] = w.x;
        wlds[wv][1][lane] = w.y;
        wlds[wv][2][lane] = w.z;
        wlds[wv][3][lane] = w.w;

        int jj = 0;
        for (; jj + 8 <= cnt; jj += 8) {
            int sb[8];
            unsigned zb[8];
            const float4 wsa = *reinterpret_cast<const float4*>(&wlds[wv][h][jj]);
            const float4 wsb = *reinterpret_cast<const float4*>(&wlds[wv][h][jj + 4]);
#pragma unroll
            for (int u = 0; u < 8; u++) sb[u] = __builtin_amdgcn_readlane(s, jj + u);
#pragma unroll
            for (int u = 0; u < 8; u++)
                zb[u] = *reinterpret_cast<const unsigned*>(Zq + (((unsigned)sb[u] << 8) + voff0));
            const float ws[8] = {wsa.x, wsa.y, wsa.z, wsa.w, wsb.x, wsb.y, wsb.z, wsb.w};
#pragma unroll
            for (int u = 0; u < 8; u++) {
                a0 = fmaf(ws[u], (float)(zb[u] & 0xffu), a0);
                a1 = fmaf(ws[u], (float)((zb[u] >> 8) & 0xffu), a1);
                a2 = fmaf(ws[u], (float)((zb[u] >> 16) & 0xffu), a2);
                a3 = fmaf(ws[u], (float)(zb[u] >> 24), a3);
                corr += ws[u];
            }
        }
        for (; jj + 4 <= cnt; jj += 4) {
            int sb[4];
            unsigned zb[4];
            const float4 wsa = *reinterpret_cast<const float4*>(&wlds[wv][h][jj]);
#pragma unroll
            for (int u = 0; u < 4; u++) sb[u] = __builtin_amdgcn_readlane(s, jj + u);
#pragma unroll
            for (int u = 0; u < 4; u++)
                zb[u] = *reinterpret_cast<const unsigned*>(Zq + (((unsigned)sb[u] << 8) + voff0));
            const float ws[4] = {wsa.x, wsa.y, wsa.z, wsa.w};
#pragma unroll
            for (int u = 0; u < 4; u++) {
                a0 = fmaf(ws[u], (float)(zb[u] & 0xffu), a0);
                a1 = fmaf(ws[u], (float)((zb[u] >> 8) & 0xffu), a1);
                a2 = fmaf(ws[u], (float)((zb[u] >> 16) & 0xffu), a2);
                a3 = fmaf(ws[u], (float)(zb[u] >> 24), a3);
                corr += ws[u];
            }
        }
        for (; jj < cnt; jj++) {
            const int s0 = __builtin_amdgcn_readlane(s, jj);
            const float ws = wlds[wv][h][jj];
            const unsigned zb = *reinterpret_cast<const unsigned*>(Zq + (((unsigned)s0 << 8) + voff0));
            a0 = fmaf(ws, (float)(zb & 0xffu), a0);
            a1 = fmaf(ws, (float)((zb >> 8) & 0xffu), a1);
            a2 = fmaf(ws, (float)((zb >> 16) & 0xffu), a2);
            a3 = fmaf(ws, (float)(zb >> 24), a3);
            corr += ws;
        }
    }

    a0 -= 128.f * corr;
    a1 -= 128.f * corr;
    a2 -= 128.f * corr;
    a3 -= 128.f * corr;

#pragma unroll
    for (int off = 1; off < 64; off <<= 1) {
        dv.x += __shfl_xor(dv.x, off, 64);
        dv.y += __shfl_xor(dv.y, off, 64);
        dv.z += __shfl_xor(dv.z, off, 64);
        dv.w += __shfl_xor(dv.w, off, 64);
    }
    const float den = (h == 0) ? dv.x : (h == 1) ? dv.y : (h == 2) ? dv.z : dv.w;
    const float inv = 1.f / (den + 1e-16f);
    float o[4] = {a0, a1, a2, a3};
#pragma unroll
    for (int j = 0; j < 4; j++) {
        float ov = o[j] * inv + bias[lane * 4 + j];
        o[j] = (ov > 0.f) ? ov : expm1f(ov);
    }
    const ushort4 vh = make_ushort4(f2bf(o[0]), f2bf(o[1]), f2bf(o[2]), f2bf(o[3]));
    *reinterpret_cast<ushort4*>(ohi + (size_t)n * 256 + lane * 4) = vh;
}

// ----------------------------- layer-2 aggregate + pool ----------------------
__global__ __launch_bounds__(256) void k_agg1(
    const unsigned short* __restrict__ Zb, const float* __restrict__ As,
    const float* __restrict__ Ad, const int* __restrict__ rowptr,
    const int* __restrict__ col, const float* __restrict__ bias,
    const int* __restrict__ batch, unsigned* __restrict__ enc, int N) {
    const int n = blockIdx.x * 4 + (threadIdx.x >> 6);
    const int lane = threadIdx.x & 63;
    if (n >= N) return;

    const int start = rowptr[n];
    const int total = rowptr[n + 1] - start;  // includes self-loop
    const int* __restrict__ cp = col + start;
    const float adn = Ad[n];

    float acc = 0.f, denom = 0.f;

    for (int base = 0; base < total; base += 64) {
        const int cnt = min(64, total - base);
        const int i = base + lane;
        int s = 0;
        float w = 0.f;
        if (i < total) {
            s = cp[i];
            w = __expf(lrelu(As[s] + adn));
        }
        denom += w;

        int jj = 0;
        for (; jj + 8 <= cnt; jj += 8) {
            int sb[8];
            float wb[8], zb[8];
#pragma unroll
            for (int u = 0; u < 8; u++) {
                sb[u] = __builtin_amdgcn_readlane(s, jj + u);
                wb[u] = readlane_f(w, jj + u);
            }
#pragma unroll
            for (int u = 0; u < 8; u++) zb[u] = bf2f(Zb[(size_t)sb[u] * 64 + lane]);
#pragma unroll
            for (int u = 0; u < 8; u++) acc = fmaf(wb[u], zb[u], acc);
        }
        for (; jj < cnt; jj++) {
            const int s0 = __builtin_amdgcn_readlane(s, jj);
            const float w0 = readlane_f(w, jj);
            acc = fmaf(w0, bf2f(Zb[(size_t)s0 * 64 + lane]), acc);
        }
    }

#pragma unroll
    for (int off = 1; off < 64; off <<= 1) denom += __shfl_xor(denom, off, 64);

    const float ov = acc / (denom + 1e-16f) + bias[lane];
    const int g = batch[n];
    atomicMax(&enc[g * 64 + lane], fenc(ov));
}

__global__ void k_decode(const unsigned* __restrict__ enc, float* __restrict__ out, int M) {
    int id = blockIdx.x * 256 + threadIdx.x;
    if (id < M) {
        unsigned e = enc[id];
        unsigned u = (e & 0x80000000u) ? (e & 0x7FFFFFFFu) : ~e;
        out[id] = __uint_as_float(u);
    }
}

// ----------------------------- launch ---------------------------------------
extern "C" void kernel_launch(void* const* d_in, const int* in_sizes, int n_in,
                              void* d_out, int out_size, void* d_ws, size_t ws_size,
                              hipStream_t stream) {
    const float* x = (const float*)d_in[0];
    const int* edge_index = (const int*)d_in[1];
    const int* batch = (const int*)d_in[2];
    const float* W0 = (const float*)d_in[3];
    const float* as0 = (const float*)d_in[4];
    const float* ad0 = (const float*)d_in[5];
    const float* b0 = (const float*)d_in[6];
    const float* W1 = (const float*)d_in[7];
    const float* as1 = (const float*)d_in[8];
    const float* ad1 = (const float*)d_in[9];
    const float* b1 = (const float*)d_in[10];
    const float* W2 = (const float*)d_in[11];
    const float* as2 = (const float*)d_in[12];
    const float* ad2 = (const float*)d_in[13];
    const float* b2 = (const float*)d_in[14];

    const int N = in_sizes[0] / 64;  // nodes
    const int E = in_sizes[1] / 2;   // edges (no self-loops)
    const int G = out_size / 64;     // graphs
    const int Et = E + N;            // edges incl. self-loops
    const int nbk = (N + 63) >> 6;   // dst buckets

    const int* srcs = edge_index;
    const int* dsts = edge_index + E;

    char* p = (char*)d_ws;
    auto alloc = [&](size_t bytes) {
        void* r = (void*)p;
        p += (bytes + 255) & ~(size_t)255;
        return r;
    };
    unsigned short* Zb = (unsigned short*)alloc((size_t)N * 64 * 2);    // bf16 z (layer 2)
    unsigned char* Zq = (unsigned char*)alloc((size_t)N * 256);         // int8 z (layer 1)
    unsigned short* xb = (unsigned short*)alloc((size_t)N * 64 * 2);    // bf16 x (layer 0)
    unsigned short* Hb = (unsigned short*)alloc((size_t)N * 256 * 2);   // h0/h1 bf16
    unsigned short* Axhi = (unsigned short*)alloc((size_t)N * 256 * 2); // aggx hi
    unsigned short* Axlo = (unsigned short*)alloc((size_t)N * 256 * 2); // aggx lo
    float* As = (float*)alloc((size_t)N * 4 * 4);
    float* Ad = (float*)alloc((size_t)N * 4 * 4);
    int* deg = (int*)alloc((size_t)N * 4);
    int* bcnt = (int*)alloc(1024 * 4);  // contiguous with deg -> one memset
    int* incl = (int*)alloc((size_t)N * 4);
    int* bsum = (int*)alloc(1024 * 4);
    int* rowptr = (int*)alloc((size_t)(N + 1) * 4);
    int* cursor = (int*)alloc((size_t)N * 4);
    int* col = (int*)alloc((size_t)Et * 4);
    uint2* rec = (uint2*)alloc((size_t)Et * 8);
    int* bbase = (int*)alloc(1024 * 4);
    int* bcur = (int*)alloc(1024 * 4);
    unsigned short* wt0h = (unsigned short*)alloc(256 * 64 * 2);
    unsigned short* wt0l = (unsigned short*)alloc(256 * 64 * 2);
    unsigned short* wt1h = (unsigned short*)alloc(256 * 256 * 2);
    unsigned short* wt1l = (unsigned short*)alloc(256 * 256 * 2);
    unsigned short* wt2h = (unsigned short*)alloc(64 * 256 * 2);
    unsigned short* wt2l = (unsigned short*)alloc(64 * 256 * 2);
    float* vs0 = (float*)alloc(4 * 64 * 4);
    float* vd0 = (float*)alloc(4 * 64 * 4);
    const int gm = (N + 127) / 128;
    float* scq = (float*)alloc((size_t)gm * 4 * 4);
    unsigned* enc = (unsigned*)alloc((size_t)G * 64 * 4);

    hipMemsetAsync(deg, 0, (size_t)((char*)(bcnt + 1024) - (char*)deg), stream);

    const int nb = (N + 255) / 256;
    const int ab = (N + 3) / 4;
    const int hb = (Et + CH - 1) / CH;
    const int encb = (G * 64 + 255) / 256;

    // CSR build: hist -> scans -> bucketize -> place
    k_hist<<<hb, 256, 0, stream>>>(dsts, E, N, deg, bcnt);
    k_scan1<<<nb, 256, 0, stream>>>(deg, incl, bsum, N);
    k_scan2<<<2, 1024, 0, stream>>>(bsum, nb, bcnt, bbase, bcur, nbk);
    k_scan3<<<nb, 256, 0, stream>>>(deg, incl, bsum, rowptr, cursor, N, nb);
    k_bucket<<<hb, 256, 0, stream>>>(srcs, dsts, E, N, bcur, rec);
    k_place<<<(Et + 255) / 256, 256, 0, stream>>>(rec, Et, cursor, col);

    k_setup<<<385 + encb, 256, 0, stream>>>(W0, W1, W2, as0, ad0, wt0h, wt0l, wt1h, wt1l,
                                            wt2h, wt2l, vs0, vd0, enc, G * 64);

    // Layer 0: As0/Ad0 + bf16 x copy; aggregate x (bf16 gather); post-GEMM
    k_att0<<<ab, 256, 0, stream>>>(x, vs0, vd0, As, Ad, xb, N);
    k_aggx<<<ab, 256, 0, stream>>>(xb, As, Ad, rowptr, col, Axhi, Axlo, N);
    k_gemm_pe<<<dim3(gm, 4), 256, 0, stream>>>(Axhi, Axlo, wt0h, wt0l, b0, Hb, N);

    // Layer 1: z GEMM (int8 out + per-quarter scales) + all-heads aggregate
    k_gemm_z<256, 256, 128, 128, 64, 1><<<dim3(gm, 2), 256, 0, stream>>>(
        Hb, wt1h, wt1l, as1, ad1, nullptr, Zq, scq, As, Ad, N);
    k_agg4<<<ab, 256, 0, stream>>>(Zq, scq, As, Ad, rowptr, col, b1, Hb, N);

    // Layer 2: z GEMM (bf16 out) + aggregate + fused pool
    k_gemm_z<256, 64, 128, 64, 64, 0><<<dim3(gm, 1), 256, 0, stream>>>(
        Hb, wt2h, wt2l, as2, ad2, Zb, nullptr, nullptr, As, Ad, N);
    k_agg1<<<ab, 256, 0, stream>>>(Zb, As, Ad, rowptr, col, b2, batch, enc, N);
    k_decode<<<(G * 64 + 255) / 256, 256, 0, stream>>>(enc, (float*)d_out, G * 64);
}